// Round 2
// baseline (466.329 us; speedup 1.0000x reference)
//
#include <hip/hip_runtime.h>
#include <hip/hip_bf16.h>

#define N_NODES 50000
#define N_EDGES 800000

// ---------------------------------------------------------------------------
// CSR build  (edge_index arrives as int32: harness converts integer inputs)
// ---------------------------------------------------------------------------
__global__ void count_deg(const int* __restrict__ ei, int* __restrict__ cnt, int E) {
    int e = blockIdx.x * blockDim.x + threadIdx.x;
    if (e >= E) return;
    int dst = ei[E + e];
    atomicAdd(&cnt[dst], 1);
}

// Single-block exclusive scan over n (<=50000) ints; offs has n+1 entries.
__global__ void scan_excl(const int* __restrict__ cnt, int* __restrict__ offs, int n) {
    __shared__ int sm[1024];
    __shared__ int carry_sm;
    const int t = threadIdx.x;
    if (t == 0) carry_sm = 0;
    __syncthreads();
    for (int base = 0; base < n; base += 1024) {
        int i = base + t;
        int v = (i < n) ? cnt[i] : 0;
        sm[t] = v;
        __syncthreads();
        for (int off = 1; off < 1024; off <<= 1) {
            int add = (t >= off) ? sm[t - off] : 0;
            __syncthreads();
            sm[t] += add;
            __syncthreads();
        }
        int carry = carry_sm;
        if (i < n) offs[i] = carry + sm[t] - v;   // exclusive
        __syncthreads();
        if (t == 1023) carry_sm = carry + sm[1023];
        __syncthreads();
    }
    if (t == 0) offs[n] = carry_sm;
}

__global__ void fill_csr(const int* __restrict__ ei, const int* __restrict__ offs,
                         int* __restrict__ cursor, int* __restrict__ csr_src, int E) {
    int e = blockIdx.x * blockDim.x + threadIdx.x;
    if (e >= E) return;
    int src = ei[e];
    int dst = ei[E + e];
    int pos = offs[dst] + atomicAdd(&cursor[dst], 1);
    csr_src[pos] = src;
}

// ---------------------------------------------------------------------------
// Mean aggregation: one wave (64 lanes) per node, 2 f32 per lane (D=128).
// ---------------------------------------------------------------------------
__global__ __launch_bounds__(256) void aggregate_mean(
        const float* __restrict__ feat, const int* __restrict__ offs,
        const int* __restrict__ csr_src, float* __restrict__ meanOut, int n) {
    int wave = (int)((blockIdx.x * blockDim.x + threadIdx.x) >> 6);
    int lane = threadIdx.x & 63;
    if (wave >= n) return;
    int beg = offs[wave], end = offs[wave + 1];
    float2 acc = make_float2(0.f, 0.f);
    for (int i = beg; i < end; ++i) {
        int s = csr_src[i];
        float2 v = *reinterpret_cast<const float2*>(feat + (size_t)s * 128 + lane * 2);
        acc.x += v.x;
        acc.y += v.y;
    }
    float inv = (end > beg) ? 1.f / (float)(end - beg) : 0.f;
    acc.x *= inv;
    acc.y *= inv;
    *reinterpret_cast<float2*>(meanOut + (size_t)wave * 128 + lane * 2) = acc;
}

// ---------------------------------------------------------------------------
// C[M,N] = relu( A1 @ B1^T (+ A2 @ B2^T) + bias ), B row-major [N,K].
// 64x64 tile, BK=32, 256 threads, 4x4 accum per thread. f32 VALU.
// ---------------------------------------------------------------------------
#define BM 64
#define BN 64
#define BK 32

__global__ __launch_bounds__(256) void combine_gemm(
        const float* __restrict__ A1, const float* __restrict__ B1,
        const float* __restrict__ A2, const float* __restrict__ B2,
        const float* __restrict__ bias, float* __restrict__ C,
        int M, int N, int K) {
    __shared__ float As[BK][BM + 4];
    __shared__ float Bs[BK][BN + 4];
    const int tid = threadIdx.x;
    const int tx = tid & 15;
    const int ty = tid >> 4;
    const int bm = blockIdx.x * BM;
    const int bn = blockIdx.y * BN;

    float acc[4][4] = {};

    for (int pass = 0; pass < 2; ++pass) {
        const float* A = pass ? A2 : A1;
        const float* B = pass ? B2 : B1;
        if (A == nullptr) break;
        for (int k0 = 0; k0 < K; k0 += BK) {
            int row = tid >> 3;            // 0..31
            int col = (tid & 7) * 4;       // 0,4,...,28
#pragma unroll
            for (int h = 0; h < 2; ++h) {
                int r = row + h * 32;
                int gm = bm + r;
                float4 v = make_float4(0.f, 0.f, 0.f, 0.f);
                if (gm < M) v = *reinterpret_cast<const float4*>(A + (size_t)gm * K + k0 + col);
                As[col + 0][r] = v.x;
                As[col + 1][r] = v.y;
                As[col + 2][r] = v.z;
                As[col + 3][r] = v.w;
                int gn = bn + r;           // N is a multiple of 64 -> in bounds
                float4 w = *reinterpret_cast<const float4*>(B + (size_t)gn * K + k0 + col);
                Bs[col + 0][r] = w.x;
                Bs[col + 1][r] = w.y;
                Bs[col + 2][r] = w.z;
                Bs[col + 3][r] = w.w;
            }
            __syncthreads();
#pragma unroll
            for (int k = 0; k < BK; ++k) {
                float4 a = *reinterpret_cast<const float4*>(&As[k][ty * 4]);
                float4 b = *reinterpret_cast<const float4*>(&Bs[k][tx * 4]);
                float av[4] = {a.x, a.y, a.z, a.w};
                float bv[4] = {b.x, b.y, b.z, b.w};
#pragma unroll
                for (int i = 0; i < 4; ++i)
#pragma unroll
                    for (int j = 0; j < 4; ++j)
                        acc[i][j] += av[i] * bv[j];
            }
            __syncthreads();
        }
    }

#pragma unroll
    for (int i = 0; i < 4; ++i) {
        int gm = bm + ty * 4 + i;
        if (gm >= M) continue;
#pragma unroll
        for (int j = 0; j < 4; ++j) {
            int gn = bn + tx * 4 + j;
            float v = acc[i][j] + bias[gn];
            C[(size_t)gm * N + gn] = v > 0.f ? v : 0.f;
        }
    }
}

// ---------------------------------------------------------------------------
extern "C" void kernel_launch(void* const* d_in, const int* in_sizes, int n_in,
                              void* d_out, int out_size, void* d_ws, size_t ws_size,
                              hipStream_t stream) {
    const float* x   = (const float*)d_in[0];
    const int*   ei  = (const int*)d_in[1];          // int32 on device
    const float* W1l = (const float*)d_in[2];
    const float* b1l = (const float*)d_in[3];
    const float* W1r = (const float*)d_in[4];
    const float* W2l = (const float*)d_in[5];
    const float* b2l = (const float*)d_in[6];
    const float* W2r = (const float*)d_in[7];
    const float* W3  = (const float*)d_in[8];
    const float* b3  = (const float*)d_in[9];
    float* out = (float*)d_out;

    const int NN = N_NODES, E = N_EDGES;

    char* base = (char*)d_ws;
    float* meanBuf = (float*)(base + 0);            // 25,600,000 B
    float* h1      = (float*)(base + 25600000);     // 25,600,000 B
    float* h2      = (float*)(base + 51200000);     // 25,600,000 B
    int*   cnt     = (int*)  (base + 76800000);     // N ints
    int*   cursor  = cnt + NN;                      // N ints
    int*   offs    = cursor + NN;                   // N+1 ints
    int*   csr     = (int*)  (base + 77400064);     // E ints

    hipMemsetAsync(cnt, 0, 2 * NN * sizeof(int), stream);

    count_deg<<<(E + 255) / 256, 256, 0, stream>>>(ei, cnt, E);
    scan_excl<<<1, 1024, 0, stream>>>(cnt, offs, NN);
    fill_csr<<<(E + 255) / 256, 256, 0, stream>>>(ei, offs, cursor, csr, E);

    // Layer 1
    aggregate_mean<<<(NN + 3) / 4, 256, 0, stream>>>(x, offs, csr, meanBuf, NN);
    combine_gemm<<<dim3((NN + BM - 1) / BM, 128 / BN), 256, 0, stream>>>(
        meanBuf, W1l, x, W1r, b1l, h1, NN, 128, 128);

    // Layer 2
    aggregate_mean<<<(NN + 3) / 4, 256, 0, stream>>>(h1, offs, csr, meanBuf, NN);
    combine_gemm<<<dim3((NN + BM - 1) / BM, 128 / BN), 256, 0, stream>>>(
        meanBuf, W2l, h1, W2r, b2l, h2, NN, 128, 128);

    // Output head: relu(h2 @ W3^T + b3), N=64
    combine_gemm<<<dim3((NN + BM - 1) / BM, 64 / BN), 256, 0, stream>>>(
        h2, W3, nullptr, nullptr, b3, out, NN, 64, 128);
}

// Round 3
// 258.399 us; speedup vs baseline: 1.8047x; 1.8047x over previous
//
#include <hip/hip_runtime.h>
#include <hip/hip_bf16.h>

#define N_NODES 50000
#define N_EDGES 800000

typedef short bf16x8 __attribute__((ext_vector_type(8)));
typedef float f32x4 __attribute__((ext_vector_type(4)));

__device__ inline unsigned short f2b(float f) {
    union { float f; unsigned u; } v; v.f = f;
    unsigned r = v.u + 0x7FFF + ((v.u >> 16) & 1);   // RNE
    return (unsigned short)(r >> 16);
}
__device__ inline float b2f(unsigned short u) {
    union { unsigned u; float f; } v; v.u = ((unsigned)u) << 16; return v.f;
}

// ---------------------------------------------------------------------------
// f32 -> bf16 conversions
// ---------------------------------------------------------------------------
__global__ __launch_bounds__(256) void cvt_bf16(const float* __restrict__ s,
                                                unsigned short* __restrict__ d, int n) {
    int idx = (blockIdx.x * 256 + threadIdx.x) * 4;
    if (idx >= n) return;
    float4 v = *reinterpret_cast<const float4*>(s + idx);
    ushort4 o;
    o.x = f2b(v.x); o.y = f2b(v.y); o.z = f2b(v.z); o.w = f2b(v.w);
    *reinterpret_cast<ushort4*>(d + idx) = o;
}

__global__ __launch_bounds__(256) void cvt_weights(
        const float* __restrict__ a, const float* __restrict__ b,
        const float* __restrict__ c, const float* __restrict__ d,
        const float* __restrict__ e,
        unsigned short* __restrict__ oa, unsigned short* __restrict__ ob,
        unsigned short* __restrict__ oc, unsigned short* __restrict__ od,
        unsigned short* __restrict__ oe) {
    int idx = (blockIdx.x * 256 + threadIdx.x) * 4;
    const float* s; unsigned short* o; int base;
    if      (idx < 16384) { s = a; o = oa; base = 0; }
    else if (idx < 32768) { s = b; o = ob; base = 16384; }
    else if (idx < 49152) { s = c; o = oc; base = 32768; }
    else if (idx < 65536) { s = d; o = od; base = 49152; }
    else if (idx < 73728) { s = e; o = oe; base = 65536; }
    else return;
    int k = idx - base;
    float4 v = *reinterpret_cast<const float4*>(s + k);
    ushort4 w;
    w.x = f2b(v.x); w.y = f2b(v.y); w.z = f2b(v.z); w.w = f2b(v.w);
    *reinterpret_cast<ushort4*>(o + k) = w;
}

// ---------------------------------------------------------------------------
// CSR build (edge_index is int32 on device)
// ---------------------------------------------------------------------------
__global__ void count_deg(const int* __restrict__ ei, int* __restrict__ cnt, int E) {
    int e = blockIdx.x * blockDim.x + threadIdx.x;
    if (e >= E) return;
    atomicAdd(&cnt[ei[E + e]], 1);
}

#define SBS 512
__global__ __launch_bounds__(SBS) void scan_pass1(const int* __restrict__ cnt,
                                                  int* __restrict__ bsum, int n) {
    __shared__ int wsum[SBS / 64];
    int t = threadIdx.x, lane = t & 63, w = t >> 6;
    int i = blockIdx.x * SBS + t;
    int v = (i < n) ? cnt[i] : 0;
#pragma unroll
    for (int o = 1; o < 64; o <<= 1) v += __shfl_xor(v, o);
    if (lane == 0) wsum[w] = v;
    __syncthreads();
    if (t == 0) {
        int s = 0;
#pragma unroll
        for (int j = 0; j < SBS / 64; ++j) s += wsum[j];
        bsum[blockIdx.x] = s;
    }
}

__global__ void scan_pass2(int* __restrict__ bsum, int nb) {
    __shared__ int sm[128];
    int t = threadIdx.x;
    int v = (t < nb) ? bsum[t] : 0;
    sm[t] = v;
    __syncthreads();
    for (int o = 1; o < 128; o <<= 1) {
        int a = (t >= o) ? sm[t - o] : 0;
        __syncthreads();
        sm[t] += a;
        __syncthreads();
    }
    if (t < nb) bsum[t] = sm[t] - v;   // exclusive
}

__global__ __launch_bounds__(SBS) void scan_pass3(const int* __restrict__ cnt,
                                                  const int* __restrict__ bsum,
                                                  int* __restrict__ offs, int n) {
    __shared__ int wsum[SBS / 64];
    int t = threadIdx.x, lane = t & 63, w = t >> 6;
    int i = blockIdx.x * SBS + t;
    int v = (i < n) ? cnt[i] : 0;
    int s = v;
#pragma unroll
    for (int o = 1; o < 64; o <<= 1) {
        int u = __shfl_up(s, o);
        if (lane >= o) s += u;
    }
    if (lane == 63) wsum[w] = s;
    __syncthreads();
    int base = bsum[blockIdx.x];
    for (int j = 0; j < w; ++j) base += wsum[j];
    int excl = base + s - v;
    if (i < n) offs[i] = excl;
    if (i == n - 1) offs[n] = excl + v;
}

__global__ void fill_csr(const int* __restrict__ ei, const int* __restrict__ offs,
                         int* __restrict__ cursor, int* __restrict__ csr_src, int E) {
    int e = blockIdx.x * blockDim.x + threadIdx.x;
    if (e >= E) return;
    int src = ei[e];
    int dst = ei[E + e];
    int pos = offs[dst] + atomicAdd(&cursor[dst], 1);
    csr_src[pos] = src;
}

// ---------------------------------------------------------------------------
// Mean aggregation over bf16 features, f32 accum, bf16 out. One wave/node.
// ---------------------------------------------------------------------------
__global__ __launch_bounds__(256) void aggregate_mean_b(
        const unsigned short* __restrict__ feat, const int* __restrict__ offs,
        const int* __restrict__ csr, unsigned short* __restrict__ out, int n) {
    int wave = (blockIdx.x * 256 + threadIdx.x) >> 6;
    int lane = threadIdx.x & 63;
    if (wave >= n) return;
    int beg = offs[wave], end = offs[wave + 1];
    float ax0 = 0.f, ay0 = 0.f, ax1 = 0.f, ay1 = 0.f;
    int i = beg;
    for (; i + 1 < end; i += 2) {
        int s0 = csr[i], s1 = csr[i + 1];
        unsigned v0 = *reinterpret_cast<const unsigned*>(feat + (size_t)s0 * 128 + lane * 2);
        unsigned v1 = *reinterpret_cast<const unsigned*>(feat + (size_t)s1 * 128 + lane * 2);
        ax0 += b2f((unsigned short)(v0 & 0xffff));
        ay0 += b2f((unsigned short)(v0 >> 16));
        ax1 += b2f((unsigned short)(v1 & 0xffff));
        ay1 += b2f((unsigned short)(v1 >> 16));
    }
    if (i < end) {
        unsigned v0 = *reinterpret_cast<const unsigned*>(feat + (size_t)csr[i] * 128 + lane * 2);
        ax0 += b2f((unsigned short)(v0 & 0xffff));
        ay0 += b2f((unsigned short)(v0 >> 16));
    }
    float inv = (end > beg) ? 1.f / (float)(end - beg) : 0.f;
    float mx = (ax0 + ax1) * inv;
    float my = (ay0 + ay1) * inv;
    ushort2 o; o.x = f2b(mx); o.y = f2b(my);
    *reinterpret_cast<ushort2*>(out + (size_t)wave * 128 + lane * 2) = o;
}

// ---------------------------------------------------------------------------
// C[M, NT*16] = relu( A1@B1^T (+ A2@B2^T) + bias ); A,B bf16 row-major, K=128.
// No LDS: B (<=32KB) is L1/L2-hot; A-frags read direct. 4 waves x 32 rows.
// ---------------------------------------------------------------------------
template<int NT, int NPASS, bool OUT_BF16>
__global__ __launch_bounds__(256) void gemm_mfma(
        const unsigned short* __restrict__ A1, const unsigned short* __restrict__ B1,
        const unsigned short* __restrict__ A2, const unsigned short* __restrict__ B2,
        const float* __restrict__ bias, void* __restrict__ Cout, int M) {
    constexpr int K = 128;
    const int lane = threadIdx.x & 63;
    const int wv = threadIdx.x >> 6;
    const int rowBase = blockIdx.x * 128 + wv * 32;
    const int fr = lane & 15;
    const int fq = lane >> 4;

    f32x4 acc[2][NT];
#pragma unroll
    for (int i = 0; i < 2; ++i)
#pragma unroll
        for (int j = 0; j < NT; ++j) acc[i][j] = (f32x4){0.f, 0.f, 0.f, 0.f};

#pragma unroll
    for (int pass = 0; pass < NPASS; ++pass) {
        const unsigned short* A = pass ? A2 : A1;
        const unsigned short* B = pass ? B2 : B1;
        bf16x8 af[2][4];
#pragma unroll
        for (int mt = 0; mt < 2; ++mt) {
            int r = rowBase + mt * 16 + fr;
            r = r < M ? r : M - 1;
            const unsigned short* p = A + (size_t)r * K + fq * 8;
#pragma unroll
            for (int ks = 0; ks < 4; ++ks)
                af[mt][ks] = *reinterpret_cast<const bf16x8*>(p + ks * 32);
        }
#pragma unroll
        for (int nt = 0; nt < NT; ++nt) {
            const unsigned short* q = B + (size_t)(nt * 16 + fr) * K + fq * 8;
#pragma unroll
            for (int ks = 0; ks < 4; ++ks) {
                bf16x8 bfr = *reinterpret_cast<const bf16x8*>(q + ks * 32);
                acc[0][nt] = __builtin_amdgcn_mfma_f32_16x16x32_bf16(af[0][ks], bfr, acc[0][nt], 0, 0, 0);
                acc[1][nt] = __builtin_amdgcn_mfma_f32_16x16x32_bf16(af[1][ks], bfr, acc[1][nt], 0, 0, 0);
            }
        }
    }

    const int NOUT = NT * 16;
#pragma unroll
    for (int mt = 0; mt < 2; ++mt) {
#pragma unroll
        for (int i = 0; i < 4; ++i) {
            int gm = rowBase + mt * 16 + fq * 4 + i;
            if (gm >= M) continue;
#pragma unroll
            for (int nt = 0; nt < NT; ++nt) {
                int gn = nt * 16 + fr;
                float v = acc[mt][nt][i] + bias[gn];
                v = v > 0.f ? v : 0.f;
                if (OUT_BF16)
                    ((unsigned short*)Cout)[(size_t)gm * NOUT + gn] = f2b(v);
                else
                    ((float*)Cout)[(size_t)gm * NOUT + gn] = v;
            }
        }
    }
}

// ---------------------------------------------------------------------------
extern "C" void kernel_launch(void* const* d_in, const int* in_sizes, int n_in,
                              void* d_out, int out_size, void* d_ws, size_t ws_size,
                              hipStream_t stream) {
    const float* x   = (const float*)d_in[0];
    const int*   ei  = (const int*)d_in[1];
    const float* W1l = (const float*)d_in[2];
    const float* b1l = (const float*)d_in[3];
    const float* W1r = (const float*)d_in[4];
    const float* W2l = (const float*)d_in[5];
    const float* b2l = (const float*)d_in[6];
    const float* W2r = (const float*)d_in[7];
    const float* W3  = (const float*)d_in[8];
    const float* b3  = (const float*)d_in[9];
    float* out = (float*)d_out;

    const int NN = N_NODES, E = N_EDGES;
    const int NB = (NN + SBS - 1) / SBS;   // 98

    char* base = (char*)d_ws;
    unsigned short* xb    = (unsigned short*)(base + 0);
    unsigned short* h1b   = (unsigned short*)(base + 12800000);
    unsigned short* h2b   = (unsigned short*)(base + 25600000);
    unsigned short* meanb = (unsigned short*)(base + 38400000);
    unsigned short* w1lb  = (unsigned short*)(base + 51200000);
    unsigned short* w1rb  = (unsigned short*)(base + 51232768);
    unsigned short* w2lb  = (unsigned short*)(base + 51265536);
    unsigned short* w2rb  = (unsigned short*)(base + 51298304);
    unsigned short* w3b   = (unsigned short*)(base + 51331072);
    int* cnt    = (int*)(base + 51347456);
    int* cursor = (int*)(base + 51547456);
    int* offs   = (int*)(base + 51747456);
    int* bsum   = (int*)(base + 51947472);
    int* csr    = (int*)(base + 51947984);

    hipMemsetAsync(cnt, 0, 400000, stream);  // cnt + cursor

    cvt_bf16<<<(NN * 128 / 4 + 255) / 256, 256, 0, stream>>>(x, xb, NN * 128);
    cvt_weights<<<72, 256, 0, stream>>>(W1l, W1r, W2l, W2r, W3, w1lb, w1rb, w2lb, w2rb, w3b);

    count_deg<<<(E + 255) / 256, 256, 0, stream>>>(ei, cnt, E);
    scan_pass1<<<NB, SBS, 0, stream>>>(cnt, bsum, NN);
    scan_pass2<<<1, 128, 0, stream>>>(bsum, NB);
    scan_pass3<<<NB, SBS, 0, stream>>>(cnt, bsum, offs, NN);
    fill_csr<<<(E + 255) / 256, 256, 0, stream>>>(ei, offs, cursor, csr, E);

    const int GB = (NN + 127) / 128;   // 391 GEMM blocks

    // Layer 1
    aggregate_mean_b<<<(NN + 3) / 4, 256, 0, stream>>>(xb, offs, csr, meanb, NN);
    gemm_mfma<8, 2, true><<<GB, 256, 0, stream>>>(meanb, w1lb, xb, w1rb, b1l, h1b, NN);

    // Layer 2
    aggregate_mean_b<<<(NN + 3) / 4, 256, 0, stream>>>(h1b, offs, csr, meanb, NN);
    gemm_mfma<8, 2, true><<<GB, 256, 0, stream>>>(meanb, w2lb, h1b, w2rb, b2l, h2b, NN);

    // Head
    gemm_mfma<4, 1, false><<<GB, 256, 0, stream>>>(h2b, w3b, nullptr, nullptr, b3, out, NN);
}

// Round 4
// 243.438 us; speedup vs baseline: 1.9156x; 1.0615x over previous
//
#include <hip/hip_runtime.h>
#include <hip/hip_bf16.h>

#define N_NODES 50000
#define N_EDGES 800000

typedef short bf16x8 __attribute__((ext_vector_type(8)));
typedef float f32x4 __attribute__((ext_vector_type(4)));

__device__ inline unsigned short f2b(float f) {
    union { float f; unsigned u; } v; v.f = f;
    unsigned r = v.u + 0x7FFF + ((v.u >> 16) & 1);   // RNE
    return (unsigned short)(r >> 16);
}
__device__ inline float b2f(unsigned short u) {
    union { unsigned u; float f; } v; v.u = ((unsigned)u) << 16; return v.f;
}

// ---------------------------------------------------------------------------
// prep: cvt x -> bf16, cvt weights -> bf16, count degrees. One flat grid.
// ---------------------------------------------------------------------------
#define XITEMS 1600000   // N_NODES*128/4
#define WITEMS 18432     // 73728/4

__global__ __launch_bounds__(256) void prep(
        const float* __restrict__ x, unsigned short* __restrict__ xb,
        const float* __restrict__ W1l, const float* __restrict__ W1r,
        const float* __restrict__ W2l, const float* __restrict__ W2r,
        const float* __restrict__ W3,
        unsigned short* __restrict__ w1lb, unsigned short* __restrict__ w1rb,
        unsigned short* __restrict__ w2lb, unsigned short* __restrict__ w2rb,
        unsigned short* __restrict__ w3b,
        const int* __restrict__ ei, int* __restrict__ cnt) {
    int gid = blockIdx.x * 256 + threadIdx.x;
    if (gid < XITEMS) {
        int idx = gid * 4;
        float4 v = *reinterpret_cast<const float4*>(x + idx);
        ushort4 o;
        o.x = f2b(v.x); o.y = f2b(v.y); o.z = f2b(v.z); o.w = f2b(v.w);
        *reinterpret_cast<ushort4*>(xb + idx) = o;
        return;
    }
    gid -= XITEMS;
    if (gid < WITEMS) {
        int idx = gid * 4;
        const float* s; unsigned short* o; int base;
        if      (idx < 16384) { s = W1l; o = w1lb; base = 0; }
        else if (idx < 32768) { s = W1r; o = w1rb; base = 16384; }
        else if (idx < 49152) { s = W2l; o = w2lb; base = 32768; }
        else if (idx < 65536) { s = W2r; o = w2rb; base = 49152; }
        else                  { s = W3;  o = w3b;  base = 65536; }
        int k = idx - base;
        float4 v = *reinterpret_cast<const float4*>(s + k);
        ushort4 w;
        w.x = f2b(v.x); w.y = f2b(v.y); w.z = f2b(v.z); w.w = f2b(v.w);
        *reinterpret_cast<ushort4*>(o + k) = w;
        return;
    }
    gid -= WITEMS;
    if (gid < N_EDGES) atomicAdd(&cnt[ei[N_EDGES + gid]], 1);
}

// ---------------------------------------------------------------------------
// Scan: pass1 block sums; pass23 scans the 98 block sums in-LDS + final scan.
// ---------------------------------------------------------------------------
#define SBS 512
__global__ __launch_bounds__(SBS) void scan_pass1(const int* __restrict__ cnt,
                                                  int* __restrict__ bsum, int n) {
    __shared__ int wsum[SBS / 64];
    int t = threadIdx.x, lane = t & 63, w = t >> 6;
    int i = blockIdx.x * SBS + t;
    int v = (i < n) ? cnt[i] : 0;
#pragma unroll
    for (int o = 1; o < 64; o <<= 1) v += __shfl_xor(v, o);
    if (lane == 0) wsum[w] = v;
    __syncthreads();
    if (t == 0) {
        int s = 0;
#pragma unroll
        for (int j = 0; j < SBS / 64; ++j) s += wsum[j];
        bsum[blockIdx.x] = s;
    }
}

__global__ __launch_bounds__(SBS) void scan_pass23(const int* __restrict__ cnt,
                                                   const int* __restrict__ bsum,
                                                   int* __restrict__ offs, int n, int nb) {
    __shared__ int bs[128];
    __shared__ int wsum[SBS / 64];
    int t = threadIdx.x, lane = t & 63, w = t >> 6;
    if (t < 128) bs[t] = (t < nb) ? bsum[t] : 0;
    __syncthreads();
    for (int o = 1; o < 128; o <<= 1) {
        int a = 0;
        if (t < 128 && t >= o) a = bs[t - o];
        __syncthreads();
        if (t < 128) bs[t] += a;
        __syncthreads();
    }
    // exclusive base for this block
    int base0 = bs[blockIdx.x] - bsum[blockIdx.x];

    int i = blockIdx.x * SBS + t;
    int v = (i < n) ? cnt[i] : 0;
    int s = v;
#pragma unroll
    for (int o = 1; o < 64; o <<= 1) {
        int u = __shfl_up(s, o);
        if (lane >= o) s += u;
    }
    if (lane == 63) wsum[w] = s;
    __syncthreads();
    int base = base0;
    for (int j = 0; j < w; ++j) base += wsum[j];
    int excl = base + s - v;
    if (i < n) offs[i] = excl;
    if (i == n - 1) offs[n] = excl + v;
}

__global__ void fill_csr(const int* __restrict__ ei, const int* __restrict__ offs,
                         int* __restrict__ cursor, int* __restrict__ csr_src, int E) {
    int e = blockIdx.x * blockDim.x + threadIdx.x;
    if (e >= E) return;
    int src = ei[e];
    int dst = ei[E + e];
    int pos = offs[dst] + atomicAdd(&cursor[dst], 1);
    csr_src[pos] = src;
}

// ---------------------------------------------------------------------------
// Mean aggregation: 16 lanes per node, 16B/lane gathers, csr broadcast via
// __shfl(width=16), inner loop unrolled x2 for 2 outstanding gathers/group.
// ---------------------------------------------------------------------------
__device__ inline void accum8(float* a, uint4 v) {
    unsigned w;
    w = v.x; a[0] += b2f((unsigned short)(w & 0xffff)); a[1] += b2f((unsigned short)(w >> 16));
    w = v.y; a[2] += b2f((unsigned short)(w & 0xffff)); a[3] += b2f((unsigned short)(w >> 16));
    w = v.z; a[4] += b2f((unsigned short)(w & 0xffff)); a[5] += b2f((unsigned short)(w >> 16));
    w = v.w; a[6] += b2f((unsigned short)(w & 0xffff)); a[7] += b2f((unsigned short)(w >> 16));
}

__global__ __launch_bounds__(256) void aggregate16(
        const unsigned short* __restrict__ feat, const int* __restrict__ offs,
        const int* __restrict__ csr, unsigned short* __restrict__ out, int n) {
    int grp = (blockIdx.x * 256 + threadIdx.x) >> 4;
    int l = threadIdx.x & 15;
    if (grp >= n) return;
    int beg = offs[grp], end = offs[grp + 1];
    int deg = end - beg;
    float acc[8] = {};
    for (int cb = 0; cb < deg; cb += 16) {
        int rem = deg - cb; if (rem > 16) rem = 16;
        int e = (cb + l < deg) ? csr[beg + cb + l] : 0;
        int j = 0;
        for (; j + 1 < rem; j += 2) {
            int s0 = __shfl(e, j, 16);
            int s1 = __shfl(e, j + 1, 16);
            uint4 v0 = *reinterpret_cast<const uint4*>(feat + (size_t)s0 * 128 + l * 8);
            uint4 v1 = *reinterpret_cast<const uint4*>(feat + (size_t)s1 * 128 + l * 8);
            accum8(acc, v0);
            accum8(acc, v1);
        }
        if (j < rem) {
            int s0 = __shfl(e, j, 16);
            uint4 v0 = *reinterpret_cast<const uint4*>(feat + (size_t)s0 * 128 + l * 8);
            accum8(acc, v0);
        }
    }
    float inv = deg > 0 ? 1.f / (float)deg : 0.f;
    uint4 o;
    o.x = (unsigned)f2b(acc[0] * inv) | ((unsigned)f2b(acc[1] * inv) << 16);
    o.y = (unsigned)f2b(acc[2] * inv) | ((unsigned)f2b(acc[3] * inv) << 16);
    o.z = (unsigned)f2b(acc[4] * inv) | ((unsigned)f2b(acc[5] * inv) << 16);
    o.w = (unsigned)f2b(acc[6] * inv) | ((unsigned)f2b(acc[7] * inv) << 16);
    *reinterpret_cast<uint4*>(out + (size_t)grp * 128 + l * 8) = o;
}

// ---------------------------------------------------------------------------
// C[M, NT*16] = relu( A1@B1^T (+ A2@B2^T) + bias ); bf16, K=128, no LDS.
// 512 threads = 8 waves x 16 rows -> 3 waves/SIMD across the grid.
// ---------------------------------------------------------------------------
template<int NT, int NPASS, bool OUT_BF16>
__global__ __launch_bounds__(512) void gemm_mfma(
        const unsigned short* __restrict__ A1, const unsigned short* __restrict__ B1,
        const unsigned short* __restrict__ A2, const unsigned short* __restrict__ B2,
        const float* __restrict__ bias, void* __restrict__ Cout, int M) {
    constexpr int K = 128;
    const int lane = threadIdx.x & 63;
    const int wv = threadIdx.x >> 6;
    const int rowBase = blockIdx.x * 128 + wv * 16;
    const int fr = lane & 15;
    const int fq = lane >> 4;

    f32x4 acc[NT];
#pragma unroll
    for (int j = 0; j < NT; ++j) acc[j] = (f32x4){0.f, 0.f, 0.f, 0.f};

#pragma unroll
    for (int pass = 0; pass < NPASS; ++pass) {
        const unsigned short* A = pass ? A2 : A1;
        const unsigned short* B = pass ? B2 : B1;
        bf16x8 af[4];
        {
            int r = rowBase + fr;
            r = r < M ? r : M - 1;
            const unsigned short* p = A + (size_t)r * K + fq * 8;
#pragma unroll
            for (int ks = 0; ks < 4; ++ks)
                af[ks] = *reinterpret_cast<const bf16x8*>(p + ks * 32);
        }
#pragma unroll
        for (int nt = 0; nt < NT; ++nt) {
            const unsigned short* q = B + (size_t)(nt * 16 + fr) * K + fq * 8;
#pragma unroll
            for (int ks = 0; ks < 4; ++ks) {
                bf16x8 bfr = *reinterpret_cast<const bf16x8*>(q + ks * 32);
                acc[nt] = __builtin_amdgcn_mfma_f32_16x16x32_bf16(af[ks], bfr, acc[nt], 0, 0, 0);
            }
        }
    }

    const int NOUT = NT * 16;
#pragma unroll
    for (int i = 0; i < 4; ++i) {
        int gm = rowBase + fq * 4 + i;
        if (gm >= M) continue;
#pragma unroll
        for (int nt = 0; nt < NT; ++nt) {
            int gn = nt * 16 + fr;
            float v = acc[nt][i] + bias[gn];
            v = v > 0.f ? v : 0.f;
            if (OUT_BF16)
                ((unsigned short*)Cout)[(size_t)gm * NOUT + gn] = f2b(v);
            else
                ((float*)Cout)[(size_t)gm * NOUT + gn] = v;
        }
    }
}

// ---------------------------------------------------------------------------
extern "C" void kernel_launch(void* const* d_in, const int* in_sizes, int n_in,
                              void* d_out, int out_size, void* d_ws, size_t ws_size,
                              hipStream_t stream) {
    const float* x   = (const float*)d_in[0];
    const int*   ei  = (const int*)d_in[1];
    const float* W1l = (const float*)d_in[2];
    const float* b1l = (const float*)d_in[3];
    const float* W1r = (const float*)d_in[4];
    const float* W2l = (const float*)d_in[5];
    const float* b2l = (const float*)d_in[6];
    const float* W2r = (const float*)d_in[7];
    const float* W3  = (const float*)d_in[8];
    const float* b3  = (const float*)d_in[9];
    float* out = (float*)d_out;

    const int NN = N_NODES, E = N_EDGES;
    const int NB = (NN + SBS - 1) / SBS;   // 98

    char* base = (char*)d_ws;
    unsigned short* xb    = (unsigned short*)(base + 0);
    unsigned short* h1b   = (unsigned short*)(base + 12800000);
    unsigned short* h2b   = (unsigned short*)(base + 25600000);
    unsigned short* meanb = (unsigned short*)(base + 38400000);
    unsigned short* w1lb  = (unsigned short*)(base + 51200000);
    unsigned short* w1rb  = (unsigned short*)(base + 51232768);
    unsigned short* w2lb  = (unsigned short*)(base + 51265536);
    unsigned short* w2rb  = (unsigned short*)(base + 51298304);
    unsigned short* w3b   = (unsigned short*)(base + 51331072);
    int* cnt    = (int*)(base + 51347456);
    int* cursor = (int*)(base + 51547456);
    int* offs   = (int*)(base + 51747456);
    int* bsum   = (int*)(base + 51947472);
    int* csr    = (int*)(base + 51947984);

    hipMemsetAsync(cnt, 0, 400000, stream);  // cnt + cursor

    const int PREP_ITEMS = XITEMS + WITEMS + E;           // 2,418,432
    prep<<<(PREP_ITEMS + 255) / 256, 256, 0, stream>>>(
        x, xb, W1l, W1r, W2l, W2r, W3, w1lb, w1rb, w2lb, w2rb, w3b, ei, cnt);

    scan_pass1<<<NB, SBS, 0, stream>>>(cnt, bsum, NN);
    scan_pass23<<<NB, SBS, 0, stream>>>(cnt, bsum, offs, NN, NB);
    fill_csr<<<(E + 255) / 256, 256, 0, stream>>>(ei, offs, cursor, csr, E);

    const int AGG_BLK = (NN * 16 + 255) / 256;   // 3125
    const int GB = (NN + 127) / 128;             // 391

    // Layer 1
    aggregate16<<<AGG_BLK, 256, 0, stream>>>(xb, offs, csr, meanb, NN);
    gemm_mfma<8, 2, true><<<GB, 512, 0, stream>>>(meanb, w1lb, xb, w1rb, b1l, h1b, NN);

    // Layer 2
    aggregate16<<<AGG_BLK, 256, 0, stream>>>(h1b, offs, csr, meanb, NN);
    gemm_mfma<8, 2, true><<<GB, 512, 0, stream>>>(meanb, w2lb, h1b, w2rb, b2l, h2b, NN);

    // Head
    gemm_mfma<4, 1, false><<<GB, 512, 0, stream>>>(h2b, w3b, nullptr, nullptr, b3, out, NN);
}

// Round 5
// 217.397 us; speedup vs baseline: 2.1451x; 1.1198x over previous
//
#include <hip/hip_runtime.h>
#include <hip/hip_bf16.h>

#define N_NODES 50000
#define N_EDGES 800000
#define NBUCK 391          // ceil(50000/128) buckets of 128 dst nodes

typedef short bf16x8 __attribute__((ext_vector_type(8)));
typedef float f32x4 __attribute__((ext_vector_type(4)));

__device__ inline unsigned short f2b(float f) {
    union { float f; unsigned u; } v; v.f = f;
    unsigned r = v.u + 0x7FFF + ((v.u >> 16) & 1);   // RNE
    return (unsigned short)(r >> 16);
}
__device__ inline float b2f(unsigned short u) {
    union { unsigned u; float f; } v; v.u = ((unsigned)u) << 16; return v.f;
}

// ---------------------------------------------------------------------------
// prep: cvt x -> bf16, cvt weights -> bf16, count degrees. One flat grid.
// ---------------------------------------------------------------------------
#define XITEMS 1600000   // N_NODES*128/4
#define WITEMS 18432     // 73728/4

__global__ __launch_bounds__(256) void prep(
        const float* __restrict__ x, unsigned short* __restrict__ xb,
        const float* __restrict__ W1l, const float* __restrict__ W1r,
        const float* __restrict__ W2l, const float* __restrict__ W2r,
        const float* __restrict__ W3,
        unsigned short* __restrict__ w1lb, unsigned short* __restrict__ w1rb,
        unsigned short* __restrict__ w2lb, unsigned short* __restrict__ w2rb,
        unsigned short* __restrict__ w3b,
        const int* __restrict__ ei, int* __restrict__ cnt) {
    int gid = blockIdx.x * 256 + threadIdx.x;
    if (gid < XITEMS) {
        int idx = gid * 4;
        float4 v = *reinterpret_cast<const float4*>(x + idx);
        ushort4 o;
        o.x = f2b(v.x); o.y = f2b(v.y); o.z = f2b(v.z); o.w = f2b(v.w);
        *reinterpret_cast<ushort4*>(xb + idx) = o;
        return;
    }
    gid -= XITEMS;
    if (gid < WITEMS) {
        int idx = gid * 4;
        const float* s; unsigned short* o; int base;
        if      (idx < 16384) { s = W1l; o = w1lb; base = 0; }
        else if (idx < 32768) { s = W1r; o = w1rb; base = 16384; }
        else if (idx < 49152) { s = W2l; o = w2lb; base = 32768; }
        else if (idx < 65536) { s = W2r; o = w2rb; base = 49152; }
        else                  { s = W3;  o = w3b;  base = 65536; }
        int k = idx - base;
        float4 v = *reinterpret_cast<const float4*>(s + k);
        ushort4 w;
        w.x = f2b(v.x); w.y = f2b(v.y); w.z = f2b(v.z); w.w = f2b(v.w);
        *reinterpret_cast<ushort4*>(o + k) = w;
        return;
    }
    gid -= WITEMS;
    if (gid < N_EDGES) atomicAdd(&cnt[ei[N_EDGES + gid]], 1);
}

// ---------------------------------------------------------------------------
// Scan: pass1 block sums; pass23 re-scans the 98 block sums in LDS + final
// node scan; also initializes bucketCursor[b] = offs[b*128].
// ---------------------------------------------------------------------------
#define SBS 512
__global__ __launch_bounds__(SBS) void scan_pass1(const int* __restrict__ cnt,
                                                  int* __restrict__ bsum, int n) {
    __shared__ int wsum[SBS / 64];
    int t = threadIdx.x, lane = t & 63, w = t >> 6;
    int i = blockIdx.x * SBS + t;
    int v = (i < n) ? cnt[i] : 0;
#pragma unroll
    for (int o = 1; o < 64; o <<= 1) v += __shfl_xor(v, o);
    if (lane == 0) wsum[w] = v;
    __syncthreads();
    if (t == 0) {
        int s = 0;
#pragma unroll
        for (int j = 0; j < SBS / 64; ++j) s += wsum[j];
        bsum[blockIdx.x] = s;
    }
}

__global__ __launch_bounds__(SBS) void scan_pass23(const int* __restrict__ cnt,
                                                   const int* __restrict__ bsum,
                                                   int* __restrict__ offs,
                                                   int* __restrict__ bucketCursor,
                                                   int n, int nb) {
    __shared__ int bs[128];
    __shared__ int wsum[SBS / 64];
    int t = threadIdx.x, lane = t & 63, w = t >> 6;
    if (t < 128) bs[t] = (t < nb) ? bsum[t] : 0;
    __syncthreads();
    for (int o = 1; o < 128; o <<= 1) {
        int a = 0;
        if (t < 128 && t >= o) a = bs[t - o];
        __syncthreads();
        if (t < 128) bs[t] += a;
        __syncthreads();
    }
    int base0 = bs[blockIdx.x] - bsum[blockIdx.x];   // exclusive block base

    int i = blockIdx.x * SBS + t;
    int v = (i < n) ? cnt[i] : 0;
    int s = v;
#pragma unroll
    for (int o = 1; o < 64; o <<= 1) {
        int u = __shfl_up(s, o);
        if (lane >= o) s += u;
    }
    if (lane == 63) wsum[w] = s;
    __syncthreads();
    int base = base0;
    for (int j = 0; j < w; ++j) base += wsum[j];
    int excl = base + s - v;
    if (i < n) {
        offs[i] = excl;
        if ((i & 127) == 0) bucketCursor[i >> 7] = excl;
    }
    if (i == n - 1) offs[n] = excl + v;
}

// ---------------------------------------------------------------------------
// CSR build pass 1: partition edges into 391 buckets of 128 dst nodes.
// Block = 512 threads x 8 edges. LDS histogram -> one global atomic per
// (block,bucket) -> append packed (dst<<32|src) pairs in dense bucket runs.
// ---------------------------------------------------------------------------
#define PB_EDGES 4096
__global__ __launch_bounds__(512) void scatter_pairs(
        const int* __restrict__ ei, int* __restrict__ bucketCursor,
        unsigned long long* __restrict__ pairBuf, int E) {
    __shared__ int hist[NBUCK];
    __shared__ int gbase[NBUCK];
    const int t = threadIdx.x;
    for (int i = t; i < NBUCK; i += 512) hist[i] = 0;
    __syncthreads();
    const int base = blockIdx.x * PB_EDGES;
    int srcv[8], dstv[8], lr[8], bk[8];
#pragma unroll
    for (int j = 0; j < 8; ++j) {
        int off = j * 512 + t;
        int idx = base + off;
        if (idx < E) {
            srcv[j] = ei[idx];
            dstv[j] = ei[E + idx];
            bk[j] = dstv[j] >> 7;
            lr[j] = atomicAdd(&hist[bk[j]], 1);
        } else {
            bk[j] = -1; srcv[j] = 0; dstv[j] = 0; lr[j] = 0;
        }
    }
    __syncthreads();
    for (int i = t; i < NBUCK; i += 512) {
        int h = hist[i];
        if (h) gbase[i] = atomicAdd(&bucketCursor[i], h);
    }
    __syncthreads();
#pragma unroll
    for (int j = 0; j < 8; ++j) {
        if (bk[j] >= 0) {
            int pos = gbase[bk[j]] + lr[j];
            pairBuf[pos] = ((unsigned long long)(unsigned)dstv[j] << 32) | (unsigned)srcv[j];
        }
    }
}

// ---------------------------------------------------------------------------
// CSR build pass 2: block per bucket; LDS node cursors; scatter src into the
// bucket's contiguous csr region (L2-resident -> dense writeback).
// ---------------------------------------------------------------------------
__global__ __launch_bounds__(512) void csr_sort(
        const unsigned long long* __restrict__ pairBuf, const int* __restrict__ offs,
        int* __restrict__ csr, int n) {
    __shared__ int ndBase[128];
    __shared__ int ndCur[128];
    const int b = blockIdx.x;
    const int t = threadIdx.x;
    const int node0 = b << 7;
    const int nNodes = min(128, n - node0);
    if (t < 128) {
        ndCur[t] = 0;
        if (t < nNodes) ndBase[t] = offs[node0 + t];
    }
    __syncthreads();
    const int start = offs[node0];
    const int end = offs[node0 + nNodes];
    for (int pos = start + t; pos < end; pos += 512) {
        unsigned long long p = pairBuf[pos];
        int s = (int)(p & 0xffffffffu);
        int d = (int)(p >> 32);
        int r = atomicAdd(&ndCur[d & 127], 1);
        csr[ndBase[d & 127] + r] = s;
    }
}

// ---------------------------------------------------------------------------
// Mean aggregation: 16 lanes per node, 16B/lane gathers, csr broadcast via
// __shfl(width=16), unrolled x4 for 4 outstanding gathers per group.
// ---------------------------------------------------------------------------
__device__ inline void accum8(float* a, uint4 v) {
    unsigned w;
    w = v.x; a[0] += b2f((unsigned short)(w & 0xffff)); a[1] += b2f((unsigned short)(w >> 16));
    w = v.y; a[2] += b2f((unsigned short)(w & 0xffff)); a[3] += b2f((unsigned short)(w >> 16));
    w = v.z; a[4] += b2f((unsigned short)(w & 0xffff)); a[5] += b2f((unsigned short)(w >> 16));
    w = v.w; a[6] += b2f((unsigned short)(w & 0xffff)); a[7] += b2f((unsigned short)(w >> 16));
}

__global__ __launch_bounds__(256) void aggregate16(
        const unsigned short* __restrict__ feat, const int* __restrict__ offs,
        const int* __restrict__ csr, unsigned short* __restrict__ out, int n) {
    int grp = (blockIdx.x * 256 + threadIdx.x) >> 4;
    int l = threadIdx.x & 15;
    if (grp >= n) return;
    int beg = offs[grp], end = offs[grp + 1];
    int deg = end - beg;
    float acc[8] = {};
    for (int cb = 0; cb < deg; cb += 16) {
        int rem = deg - cb; if (rem > 16) rem = 16;
        int e = (cb + l < deg) ? csr[beg + cb + l] : 0;
        int j = 0;
        for (; j + 3 < rem; j += 4) {
            int s0 = __shfl(e, j, 16);
            int s1 = __shfl(e, j + 1, 16);
            int s2 = __shfl(e, j + 2, 16);
            int s3 = __shfl(e, j + 3, 16);
            uint4 v0 = *reinterpret_cast<const uint4*>(feat + (size_t)s0 * 128 + l * 8);
            uint4 v1 = *reinterpret_cast<const uint4*>(feat + (size_t)s1 * 128 + l * 8);
            uint4 v2 = *reinterpret_cast<const uint4*>(feat + (size_t)s2 * 128 + l * 8);
            uint4 v3 = *reinterpret_cast<const uint4*>(feat + (size_t)s3 * 128 + l * 8);
            accum8(acc, v0); accum8(acc, v1); accum8(acc, v2); accum8(acc, v3);
        }
        for (; j < rem; ++j) {
            int s0 = __shfl(e, j, 16);
            uint4 v0 = *reinterpret_cast<const uint4*>(feat + (size_t)s0 * 128 + l * 8);
            accum8(acc, v0);
        }
    }
    float inv = deg > 0 ? 1.f / (float)deg : 0.f;
    uint4 o;
    o.x = (unsigned)f2b(acc[0] * inv) | ((unsigned)f2b(acc[1] * inv) << 16);
    o.y = (unsigned)f2b(acc[2] * inv) | ((unsigned)f2b(acc[3] * inv) << 16);
    o.z = (unsigned)f2b(acc[4] * inv) | ((unsigned)f2b(acc[5] * inv) << 16);
    o.w = (unsigned)f2b(acc[6] * inv) | ((unsigned)f2b(acc[7] * inv) << 16);
    *reinterpret_cast<uint4*>(out + (size_t)grp * 128 + l * 8) = o;
}

// ---------------------------------------------------------------------------
// C[M, NT*16] = relu( A1@B1^T (+ A2@B2^T) + bias ); bf16, K=128, no LDS.
// 512 threads = 8 waves x 16 rows.
// ---------------------------------------------------------------------------
template<int NT, int NPASS, bool OUT_BF16>
__global__ __launch_bounds__(512) void gemm_mfma(
        const unsigned short* __restrict__ A1, const unsigned short* __restrict__ B1,
        const unsigned short* __restrict__ A2, const unsigned short* __restrict__ B2,
        const float* __restrict__ bias, void* __restrict__ Cout, int M) {
    constexpr int K = 128;
    const int lane = threadIdx.x & 63;
    const int wv = threadIdx.x >> 6;
    const int rowBase = blockIdx.x * 128 + wv * 16;
    const int fr = lane & 15;
    const int fq = lane >> 4;

    f32x4 acc[NT];
#pragma unroll
    for (int j = 0; j < NT; ++j) acc[j] = (f32x4){0.f, 0.f, 0.f, 0.f};

#pragma unroll
    for (int pass = 0; pass < NPASS; ++pass) {
        const unsigned short* A = pass ? A2 : A1;
        const unsigned short* B = pass ? B2 : B1;
        bf16x8 af[4];
        {
            int r = rowBase + fr;
            r = r < M ? r : M - 1;
            const unsigned short* p = A + (size_t)r * K + fq * 8;
#pragma unroll
            for (int ks = 0; ks < 4; ++ks)
                af[ks] = *reinterpret_cast<const bf16x8*>(p + ks * 32);
        }
#pragma unroll
        for (int nt = 0; nt < NT; ++nt) {
            const unsigned short* q = B + (size_t)(nt * 16 + fr) * K + fq * 8;
#pragma unroll
            for (int ks = 0; ks < 4; ++ks) {
                bf16x8 bfr = *reinterpret_cast<const bf16x8*>(q + ks * 32);
                acc[nt] = __builtin_amdgcn_mfma_f32_16x16x32_bf16(af[ks], bfr, acc[nt], 0, 0, 0);
            }
        }
    }

    const int NOUT = NT * 16;
#pragma unroll
    for (int i = 0; i < 4; ++i) {
        int gm = rowBase + fq * 4 + i;
        if (gm >= M) continue;
#pragma unroll
        for (int nt = 0; nt < NT; ++nt) {
            int gn = nt * 16 + fr;
            float v = acc[nt][i] + bias[gn];
            v = v > 0.f ? v : 0.f;
            if (OUT_BF16)
                ((unsigned short*)Cout)[(size_t)gm * NOUT + gn] = f2b(v);
            else
                ((float*)Cout)[(size_t)gm * NOUT + gn] = v;
        }
    }
}

// ---------------------------------------------------------------------------
extern "C" void kernel_launch(void* const* d_in, const int* in_sizes, int n_in,
                              void* d_out, int out_size, void* d_ws, size_t ws_size,
                              hipStream_t stream) {
    const float* x   = (const float*)d_in[0];
    const int*   ei  = (const int*)d_in[1];
    const float* W1l = (const float*)d_in[2];
    const float* b1l = (const float*)d_in[3];
    const float* W1r = (const float*)d_in[4];
    const float* W2l = (const float*)d_in[5];
    const float* b2l = (const float*)d_in[6];
    const float* W2r = (const float*)d_in[7];
    const float* W3  = (const float*)d_in[8];
    const float* b3  = (const float*)d_in[9];
    float* out = (float*)d_out;

    const int NN = N_NODES, E = N_EDGES;
    const int NB = (NN + SBS - 1) / SBS;   // 98

    char* base = (char*)d_ws;
    unsigned short* xb    = (unsigned short*)(base + 0);
    unsigned short* h1b   = (unsigned short*)(base + 12800000);
    unsigned short* h2b   = (unsigned short*)(base + 25600000);
    unsigned short* meanb = (unsigned short*)(base + 38400000);
    unsigned short* w1lb  = (unsigned short*)(base + 51200000);
    unsigned short* w1rb  = (unsigned short*)(base + 51232768);
    unsigned short* w2lb  = (unsigned short*)(base + 51265536);
    unsigned short* w2rb  = (unsigned short*)(base + 51298304);
    unsigned short* w3b   = (unsigned short*)(base + 51331072);
    int* cnt          = (int*)(base + 51347456);   // 200,000 B
    int* offs         = (int*)(base + 51547456);   // 200,004 B (+pad)
    int* bsum         = (int*)(base + 51747472);   // 512 B
    int* bucketCursor = (int*)(base + 51747984);   // 1,564 B (+pad)
    int* csr          = (int*)(base + 51749632);   // 3,200,000 B
    unsigned long long* pairBuf = (unsigned long long*)(base + 54949632); // 6,400,000 B

    hipMemsetAsync(cnt, 0, 200000, stream);

    const int PREP_ITEMS = XITEMS + WITEMS + E;           // 2,418,432
    prep<<<(PREP_ITEMS + 255) / 256, 256, 0, stream>>>(
        x, xb, W1l, W1r, W2l, W2r, W3, w1lb, w1rb, w2lb, w2rb, w3b, ei, cnt);

    scan_pass1<<<NB, SBS, 0, stream>>>(cnt, bsum, NN);
    scan_pass23<<<NB, SBS, 0, stream>>>(cnt, bsum, offs, bucketCursor, NN, NB);
    scatter_pairs<<<(E + PB_EDGES - 1) / PB_EDGES, 512, 0, stream>>>(ei, bucketCursor, pairBuf, E);
    csr_sort<<<NBUCK, 512, 0, stream>>>(pairBuf, offs, csr, NN);

    const int AGG_BLK = (NN * 16 + 255) / 256;   // 3125
    const int GB = (NN + 127) / 128;             // 391

    // Layer 1
    aggregate16<<<AGG_BLK, 256, 0, stream>>>(xb, offs, csr, meanb, NN);
    gemm_mfma<8, 2, true><<<GB, 512, 0, stream>>>(meanb, w1lb, xb, w1rb, b1l, h1b, NN);

    // Layer 2
    aggregate16<<<AGG_BLK, 256, 0, stream>>>(h1b, offs, csr, meanb, NN);
    gemm_mfma<8, 2, true><<<GB, 512, 0, stream>>>(meanb, w2lb, h1b, w2rb, b2l, h2b, NN);

    // Head
    gemm_mfma<4, 1, false><<<GB, 512, 0, stream>>>(h2b, w3b, nullptr, nullptr, b3, out, NN);
}

// Round 6
// 182.056 us; speedup vs baseline: 2.5615x; 1.1941x over previous
//
#include <hip/hip_runtime.h>
#include <hip/hip_bf16.h>

#define N_NODES 50000
#define N_EDGES 800000
#define NBUCK 391          // ceil(50000/128) buckets of 128 dst nodes
#define CAP 4096           // pairBuf slots per bucket (expected 2046, >>6 sigma)

typedef short bf16x8 __attribute__((ext_vector_type(8)));
typedef float f32x4 __attribute__((ext_vector_type(4)));

__device__ inline unsigned short f2b(float f) {
    union { float f; unsigned u; } v; v.f = f;
    unsigned r = v.u + 0x7FFF + ((v.u >> 16) & 1);   // RNE
    return (unsigned short)(r >> 16);
}
__device__ inline float b2f(unsigned short u) {
    union { unsigned u; float f; } v; v.u = ((unsigned)u) << 16; return v.f;
}

// ---------------------------------------------------------------------------
// prep: cvt x -> bf16, cvt weights -> bf16. Pure copy, no atomics.
// ---------------------------------------------------------------------------
#define XITEMS 1600000   // N_NODES*128/4
#define WITEMS 18432     // 73728/4

__global__ __launch_bounds__(256) void prep(
        const float* __restrict__ x, unsigned short* __restrict__ xb,
        const float* __restrict__ W1l, const float* __restrict__ W1r,
        const float* __restrict__ W2l, const float* __restrict__ W2r,
        const float* __restrict__ W3,
        unsigned short* __restrict__ w1lb, unsigned short* __restrict__ w1rb,
        unsigned short* __restrict__ w2lb, unsigned short* __restrict__ w2rb,
        unsigned short* __restrict__ w3b) {
    int gid = blockIdx.x * 256 + threadIdx.x;
    if (gid < XITEMS) {
        int idx = gid * 4;
        float4 v = *reinterpret_cast<const float4*>(x + idx);
        ushort4 o;
        o.x = f2b(v.x); o.y = f2b(v.y); o.z = f2b(v.z); o.w = f2b(v.w);
        *reinterpret_cast<ushort4*>(xb + idx) = o;
        return;
    }
    gid -= XITEMS;
    if (gid < WITEMS) {
        int idx = gid * 4;
        const float* s; unsigned short* o; int base;
        if      (idx < 16384) { s = W1l; o = w1lb; base = 0; }
        else if (idx < 32768) { s = W1r; o = w1rb; base = 16384; }
        else if (idx < 49152) { s = W2l; o = w2lb; base = 32768; }
        else if (idx < 65536) { s = W2r; o = w2rb; base = 49152; }
        else                  { s = W3;  o = w3b;  base = 65536; }
        int k = idx - base;
        float4 v = *reinterpret_cast<const float4*>(s + k);
        ushort4 w;
        w.x = f2b(v.x); w.y = f2b(v.y); w.z = f2b(v.z); w.w = f2b(v.w);
        *reinterpret_cast<ushort4*>(o + k) = w;
    }
}

// ---------------------------------------------------------------------------
// CSR pass 1: partition edges into fixed-capacity bucket regions.
// Only bucket-level global atomics (391 per block).
// ---------------------------------------------------------------------------
#define PB_EDGES 4096
__global__ __launch_bounds__(512) void scatter_pairs(
        const int* __restrict__ ei, int* __restrict__ bucketCount,
        unsigned long long* __restrict__ pairBuf, int E) {
    __shared__ int hist[NBUCK];
    __shared__ int gbase[NBUCK];
    const int t = threadIdx.x;
    for (int i = t; i < NBUCK; i += 512) hist[i] = 0;
    __syncthreads();
    const int base = blockIdx.x * PB_EDGES;
    int srcv[8], dstv[8], lr[8], bk[8];
#pragma unroll
    for (int j = 0; j < 8; ++j) {
        int idx = base + j * 512 + t;
        if (idx < E) {
            srcv[j] = ei[idx];
            dstv[j] = ei[E + idx];
            bk[j] = dstv[j] >> 7;
            lr[j] = atomicAdd(&hist[bk[j]], 1);
        } else {
            bk[j] = -1; srcv[j] = 0; dstv[j] = 0; lr[j] = 0;
        }
    }
    __syncthreads();
    for (int i = t; i < NBUCK; i += 512) {
        int h = hist[i];
        if (h) gbase[i] = i * CAP + atomicAdd(&bucketCount[i], h);
    }
    __syncthreads();
#pragma unroll
    for (int j = 0; j < 8; ++j) {
        if (bk[j] >= 0) {
            int pos = gbase[bk[j]] + lr[j];
            pairBuf[pos] = ((unsigned long long)(unsigned)dstv[j] << 32) | (unsigned)srcv[j];
        }
    }
}

// ---------------------------------------------------------------------------
// CSR pass 2: block per bucket. In-LDS scan of 391 bucket counts (redundant
// per block) -> csr base; LDS per-node degree hist + scan -> offs; scatter
// src into the bucket's contiguous csr region.
// ---------------------------------------------------------------------------
__global__ __launch_bounds__(512) void csr_sort(
        const unsigned long long* __restrict__ pairBuf,
        const int* __restrict__ bucketCount,
        int* __restrict__ offs, int* __restrict__ csr, int n) {
    __shared__ int sm[512];
    __shared__ int nb[128];
    __shared__ int nc[128];
    const int b = blockIdx.x, t = threadIdx.x;
    int v = (t < NBUCK) ? bucketCount[t] : 0;
    sm[t] = v;
    __syncthreads();
    for (int o = 1; o < 512; o <<= 1) {
        int a = (t >= o) ? sm[t - o] : 0;
        __syncthreads();
        sm[t] += a;
        __syncthreads();
    }
    const int count = bucketCount[b];
    const int base = sm[b] - count;       // exclusive prefix over buckets
    const int node0 = b << 7;
    const int nN = min(128, n - node0);
    if (t < 128) nc[t] = 0;
    __syncthreads();
    const unsigned long long* pb = pairBuf + (size_t)b * CAP;
    for (int i = t; i < count; i += 512) {
        int d = ((int)(pb[i] >> 32)) & 127;
        atomicAdd(&nc[d], 1);
    }
    __syncthreads();
    if (t < 128) sm[t] = nc[t];
    __syncthreads();
    for (int o = 1; o < 128; o <<= 1) {
        int a = 0;
        if (t < 128 && t >= o) a = sm[t - o];
        __syncthreads();
        if (t < 128) sm[t] += a;
        __syncthreads();
    }
    if (t < 128) nb[t] = base + sm[t] - nc[t];   // exclusive per-node base
    __syncthreads();
    if (t < nN) offs[node0 + t] = nb[t];
    if (b == NBUCK - 1 && t == 0) offs[n] = base + count;
    if (t < 128) nc[t] = 0;
    __syncthreads();
    for (int i = t; i < count; i += 512) {
        unsigned long long p = pb[i];
        int d = ((int)(p >> 32)) & 127;
        int r = atomicAdd(&nc[d], 1);
        csr[nb[d] + r] = (int)(p & 0xffffffffu);
    }
}

// ---------------------------------------------------------------------------
// Fused layer: gather-mean(64 nodes) -> swizzled LDS A-tile -> MFMA GEMM.
// LAYER2 additionally: h2 C-frags -> LDS -> head MFMA -> f32 out.
// Block: 256 threads (4 waves), 64 nodes. XOR swizzle (row&7)<<4 on LDS.
// ---------------------------------------------------------------------------
__device__ inline void accum8(float* a, uint4 v) {
    unsigned w;
    w = v.x; a[0] += b2f((unsigned short)(w & 0xffff)); a[1] += b2f((unsigned short)(w >> 16));
    w = v.y; a[2] += b2f((unsigned short)(w & 0xffff)); a[3] += b2f((unsigned short)(w >> 16));
    w = v.z; a[4] += b2f((unsigned short)(w & 0xffff)); a[5] += b2f((unsigned short)(w >> 16));
    w = v.w; a[6] += b2f((unsigned short)(w & 0xffff)); a[7] += b2f((unsigned short)(w >> 16));
}

template<bool LAYER2>
__global__ __launch_bounds__(256) void fused_layer(
        const unsigned short* __restrict__ feat,      // gather source == A2
        const int* __restrict__ offs, const int* __restrict__ csr,
        const unsigned short* __restrict__ Bl, const unsigned short* __restrict__ Br,
        const float* __restrict__ bias,
        const unsigned short* __restrict__ W3, const float* __restrict__ b3,
        void* __restrict__ outP, int n) {
    __shared__ char lds[64 * 256];
    const int t = threadIdx.x;
    const int n0 = blockIdx.x * 64;

    // ---- phase 1: mean-aggregate 64 nodes into LDS (bf16, swizzled) ----
    {
        const int g = t >> 4, l = t & 15;
        for (int i = 0; i < 4; ++i) {
            int node = n0 + g * 4 + i;
            if (node < n) {
                int beg = offs[node], end = offs[node + 1];
                int deg = end - beg;
                float acc[8] = {};
                for (int cb = 0; cb < deg; cb += 16) {
                    int rem = deg - cb; if (rem > 16) rem = 16;
                    int e = (cb + l < deg) ? csr[beg + cb + l] : 0;
                    int j = 0;
                    for (; j + 3 < rem; j += 4) {
                        int s0 = __shfl(e, j, 16);
                        int s1 = __shfl(e, j + 1, 16);
                        int s2 = __shfl(e, j + 2, 16);
                        int s3 = __shfl(e, j + 3, 16);
                        uint4 v0 = *reinterpret_cast<const uint4*>(feat + (size_t)s0 * 128 + l * 8);
                        uint4 v1 = *reinterpret_cast<const uint4*>(feat + (size_t)s1 * 128 + l * 8);
                        uint4 v2 = *reinterpret_cast<const uint4*>(feat + (size_t)s2 * 128 + l * 8);
                        uint4 v3 = *reinterpret_cast<const uint4*>(feat + (size_t)s3 * 128 + l * 8);
                        accum8(acc, v0); accum8(acc, v1); accum8(acc, v2); accum8(acc, v3);
                    }
                    for (; j < rem; ++j) {
                        int s0 = __shfl(e, j, 16);
                        uint4 v0 = *reinterpret_cast<const uint4*>(feat + (size_t)s0 * 128 + l * 8);
                        accum8(acc, v0);
                    }
                }
                float inv = deg > 0 ? 1.f / (float)deg : 0.f;
                uint4 o;
                o.x = (unsigned)f2b(acc[0] * inv) | ((unsigned)f2b(acc[1] * inv) << 16);
                o.y = (unsigned)f2b(acc[2] * inv) | ((unsigned)f2b(acc[3] * inv) << 16);
                o.z = (unsigned)f2b(acc[4] * inv) | ((unsigned)f2b(acc[5] * inv) << 16);
                o.w = (unsigned)f2b(acc[6] * inv) | ((unsigned)f2b(acc[7] * inv) << 16);
                int r = node - n0;
                int off = (r * 256 + l * 16) ^ ((r & 7) << 4);
                *reinterpret_cast<uint4*>(lds + off) = o;
            }
        }
    }
    __syncthreads();

    // ---- phase 2: C = relu(mean @ Bl^T + feat @ Br^T + bias) ----
    const int lane = t & 63, wv = t >> 6;
    const int fr = lane & 15, fq = lane >> 4;
    const int rl = wv * 16 + fr;         // block-local A row for fragments

    f32x4 acc[8];
#pragma unroll
    for (int j = 0; j < 8; ++j) acc[j] = (f32x4){0.f, 0.f, 0.f, 0.f};

    bf16x8 a1[4], a2[4];
#pragma unroll
    for (int ks = 0; ks < 4; ++ks) {
        int off = (rl * 256 + ks * 64 + fq * 16) ^ ((rl & 7) << 4);
        a1[ks] = *reinterpret_cast<const bf16x8*>(lds + off);
    }
    {
        int gr = n0 + rl; gr = gr < n ? gr : n - 1;
        const unsigned short* p = feat + (size_t)gr * 128 + fq * 8;
#pragma unroll
        for (int ks = 0; ks < 4; ++ks)
            a2[ks] = *reinterpret_cast<const bf16x8*>(p + ks * 32);
    }
#pragma unroll
    for (int nt = 0; nt < 8; ++nt) {
        const unsigned short* ql = Bl + (size_t)(nt * 16 + fr) * 128 + fq * 8;
        const unsigned short* qr = Br + (size_t)(nt * 16 + fr) * 128 + fq * 8;
#pragma unroll
        for (int ks = 0; ks < 4; ++ks) {
            bf16x8 bl = *reinterpret_cast<const bf16x8*>(ql + ks * 32);
            acc[nt] = __builtin_amdgcn_mfma_f32_16x16x32_bf16(a1[ks], bl, acc[nt], 0, 0, 0);
        }
#pragma unroll
        for (int ks = 0; ks < 4; ++ks) {
            bf16x8 br = *reinterpret_cast<const bf16x8*>(qr + ks * 32);
            acc[nt] = __builtin_amdgcn_mfma_f32_16x16x32_bf16(a2[ks], br, acc[nt], 0, 0, 0);
        }
    }

    if (!LAYER2) {
        unsigned short* h1 = (unsigned short*)outP;
#pragma unroll
        for (int i = 0; i < 4; ++i) {
            int gm = n0 + wv * 16 + fq * 4 + i;
            if (gm >= n) continue;
#pragma unroll
            for (int nt = 0; nt < 8; ++nt) {
                int c = nt * 16 + fr;
                float v = acc[nt][i] + bias[c];
                h1[(size_t)gm * 128 + c] = f2b(v > 0.f ? v : 0.f);
            }
        }
    } else {
        __syncthreads();   // everyone done reading mean tile
#pragma unroll
        for (int i = 0; i < 4; ++i) {
            int rL = wv * 16 + fq * 4 + i;
#pragma unroll
            for (int nt = 0; nt < 8; ++nt) {
                int c = nt * 16 + fr;
                float v = acc[nt][i] + bias[c];
                int off = (rL * 256 + c * 2) ^ ((rL & 7) << 4);
                *reinterpret_cast<unsigned short*>(lds + off) = f2b(v > 0.f ? v : 0.f);
            }
        }
        __syncthreads();
        // ---- phase 3: out = relu(h2 @ W3^T + b3), 64 cols, f32 ----
        f32x4 acc3[4];
#pragma unroll
        for (int j = 0; j < 4; ++j) acc3[j] = (f32x4){0.f, 0.f, 0.f, 0.f};
        bf16x8 a3[4];
#pragma unroll
        for (int ks = 0; ks < 4; ++ks) {
            int off = (rl * 256 + ks * 64 + fq * 16) ^ ((rl & 7) << 4);
            a3[ks] = *reinterpret_cast<const bf16x8*>(lds + off);
        }
#pragma unroll
        for (int nt = 0; nt < 4; ++nt) {
            const unsigned short* q = W3 + (size_t)(nt * 16 + fr) * 128 + fq * 8;
#pragma unroll
            for (int ks = 0; ks < 4; ++ks) {
                bf16x8 bw = *reinterpret_cast<const bf16x8*>(q + ks * 32);
                acc3[nt] = __builtin_amdgcn_mfma_f32_16x16x32_bf16(a3[ks], bw, acc3[nt], 0, 0, 0);
            }
        }
        float* out = (float*)outP;
#pragma unroll
        for (int i = 0; i < 4; ++i) {
            int gm = n0 + wv * 16 + fq * 4 + i;
            if (gm >= n) continue;
#pragma unroll
            for (int nt = 0; nt < 4; ++nt) {
                int c = nt * 16 + fr;
                float v = acc3[nt][i] + b3[c];
                out[(size_t)gm * 64 + c] = v > 0.f ? v : 0.f;
            }
        }
    }
}

// ---------------------------------------------------------------------------
extern "C" void kernel_launch(void* const* d_in, const int* in_sizes, int n_in,
                              void* d_out, int out_size, void* d_ws, size_t ws_size,
                              hipStream_t stream) {
    const float* x   = (const float*)d_in[0];
    const int*   ei  = (const int*)d_in[1];
    const float* W1l = (const float*)d_in[2];
    const float* b1l = (const float*)d_in[3];
    const float* W1r = (const float*)d_in[4];
    const float* W2l = (const float*)d_in[5];
    const float* b2l = (const float*)d_in[6];
    const float* W2r = (const float*)d_in[7];
    const float* W3  = (const float*)d_in[8];
    const float* b3  = (const float*)d_in[9];
    float* out = (float*)d_out;

    const int NN = N_NODES, E = N_EDGES;

    char* base = (char*)d_ws;
    unsigned short* xb   = (unsigned short*)(base + 0);         // 12,800,000
    unsigned short* h1b  = (unsigned short*)(base + 12800000);  // 12,800,000
    unsigned short* w1lb = (unsigned short*)(base + 25600000);
    unsigned short* w1rb = (unsigned short*)(base + 25632768);
    unsigned short* w2lb = (unsigned short*)(base + 25665536);
    unsigned short* w2rb = (unsigned short*)(base + 25698304);
    unsigned short* w3b  = (unsigned short*)(base + 25731072);  // 16,384
    int* offs            = (int*)(base + 25747456);             // 200,064
    int* bucketCount     = (int*)(base + 25947520);             // 1,600
    int* csr             = (int*)(base + 25949120);             // 3,200,000
    unsigned long long* pairBuf = (unsigned long long*)(base + 29149120 + 4); // align
    pairBuf = (unsigned long long*)(base + 29149128);           // 12,812,288 -> end ~42MB

    hipMemsetAsync(bucketCount, 0, 1600, stream);

    const int PREP_ITEMS = XITEMS + WITEMS;   // 1,618,432
    prep<<<(PREP_ITEMS + 255) / 256, 256, 0, stream>>>(
        x, xb, W1l, W1r, W2l, W2r, W3, w1lb, w1rb, w2lb, w2rb, w3b);

    scatter_pairs<<<(E + PB_EDGES - 1) / PB_EDGES, 512, 0, stream>>>(ei, bucketCount, pairBuf, E);
    csr_sort<<<NBUCK, 512, 0, stream>>>(pairBuf, bucketCount, offs, csr, NN);

    const int FB = (NN + 63) / 64;   // 782

    fused_layer<false><<<FB, 256, 0, stream>>>(
        xb, offs, csr, w1lb, w1rb, b1l, nullptr, nullptr, h1b, NN);

    fused_layer<true><<<FB, 256, 0, stream>>>(
        h1b, offs, csr, w2lb, w2rb, b2l, w3b, b3, out, NN);
}

// Round 7
// 169.297 us; speedup vs baseline: 2.7545x; 1.0754x over previous
//
#include <hip/hip_runtime.h>
#include <hip/hip_bf16.h>

#define N_NODES 50000
#define N_EDGES 800000
#define NBUCK 391          // ceil(50000/128) buckets of 128 dst nodes
#define CAP 4096           // pairBuf slots per bucket (expected 2046, >>6 sigma)

typedef short bf16x8 __attribute__((ext_vector_type(8)));
typedef float f32x4 __attribute__((ext_vector_type(4)));

__device__ inline unsigned short f2b(float f) {
    union { float f; unsigned u; } v; v.f = f;
    unsigned r = v.u + 0x7FFF + ((v.u >> 16) & 1);   // RNE
    return (unsigned short)(r >> 16);
}
__device__ inline float b2f(unsigned short u) {
    union { unsigned u; float f; } v; v.u = ((unsigned)u) << 16; return v.f;
}

// ---------------------------------------------------------------------------
// prep: cvt x -> bf16, cvt weights -> bf16. Pure copy, no atomics.
// ---------------------------------------------------------------------------
#define XITEMS 1600000   // N_NODES*128/4
#define WITEMS 18432     // 73728/4

__global__ __launch_bounds__(256) void prep(
        const float* __restrict__ x, unsigned short* __restrict__ xb,
        const float* __restrict__ W1l, const float* __restrict__ W1r,
        const float* __restrict__ W2l, const float* __restrict__ W2r,
        const float* __restrict__ W3,
        unsigned short* __restrict__ w1lb, unsigned short* __restrict__ w1rb,
        unsigned short* __restrict__ w2lb, unsigned short* __restrict__ w2rb,
        unsigned short* __restrict__ w3b) {
    int gid = blockIdx.x * 256 + threadIdx.x;
    if (gid < XITEMS) {
        int idx = gid * 4;
        float4 v = *reinterpret_cast<const float4*>(x + idx);
        ushort4 o;
        o.x = f2b(v.x); o.y = f2b(v.y); o.z = f2b(v.z); o.w = f2b(v.w);
        *reinterpret_cast<ushort4*>(xb + idx) = o;
        return;
    }
    gid -= XITEMS;
    if (gid < WITEMS) {
        int idx = gid * 4;
        const float* s; unsigned short* o; int base;
        if      (idx < 16384) { s = W1l; o = w1lb; base = 0; }
        else if (idx < 32768) { s = W1r; o = w1rb; base = 16384; }
        else if (idx < 49152) { s = W2l; o = w2lb; base = 32768; }
        else if (idx < 65536) { s = W2r; o = w2rb; base = 49152; }
        else                  { s = W3;  o = w3b;  base = 65536; }
        int k = idx - base;
        float4 v = *reinterpret_cast<const float4*>(s + k);
        ushort4 w;
        w.x = f2b(v.x); w.y = f2b(v.y); w.z = f2b(v.z); w.w = f2b(v.w);
        *reinterpret_cast<ushort4*>(o + k) = w;
    }
}

// ---------------------------------------------------------------------------
// CSR pass 1: partition edges into fixed-capacity bucket regions.
// ---------------------------------------------------------------------------
#define PB_EDGES 4096
__global__ __launch_bounds__(512) void scatter_pairs(
        const int* __restrict__ ei, int* __restrict__ bucketCount,
        unsigned long long* __restrict__ pairBuf, int E) {
    __shared__ int hist[NBUCK];
    __shared__ int gbase[NBUCK];
    const int t = threadIdx.x;
    for (int i = t; i < NBUCK; i += 512) hist[i] = 0;
    __syncthreads();
    const int base = blockIdx.x * PB_EDGES;
    int srcv[8], dstv[8], lr[8], bk[8];
#pragma unroll
    for (int j = 0; j < 8; ++j) {
        int idx = base + j * 512 + t;
        if (idx < E) {
            srcv[j] = ei[idx];
            dstv[j] = ei[E + idx];
            bk[j] = dstv[j] >> 7;
            lr[j] = atomicAdd(&hist[bk[j]], 1);
        } else {
            bk[j] = -1; srcv[j] = 0; dstv[j] = 0; lr[j] = 0;
        }
    }
    __syncthreads();
    for (int i = t; i < NBUCK; i += 512) {
        int h = hist[i];
        if (h) gbase[i] = i * CAP + atomicAdd(&bucketCount[i], h);
    }
    __syncthreads();
#pragma unroll
    for (int j = 0; j < 8; ++j) {
        if (bk[j] >= 0) {
            int pos = gbase[bk[j]] + lr[j];
            pairBuf[pos] = ((unsigned long long)(unsigned)dstv[j] << 32) | (unsigned)srcv[j];
        }
    }
}

// ---------------------------------------------------------------------------
// CSR pass 2: block per bucket -> offs + csr.
// ---------------------------------------------------------------------------
__global__ __launch_bounds__(512) void csr_sort(
        const unsigned long long* __restrict__ pairBuf,
        const int* __restrict__ bucketCount,
        int* __restrict__ offs, int* __restrict__ csr, int n) {
    __shared__ int sm[512];
    __shared__ int nb[128];
    __shared__ int nc[128];
    const int b = blockIdx.x, t = threadIdx.x;
    int v = (t < NBUCK) ? bucketCount[t] : 0;
    sm[t] = v;
    __syncthreads();
    for (int o = 1; o < 512; o <<= 1) {
        int a = (t >= o) ? sm[t - o] : 0;
        __syncthreads();
        sm[t] += a;
        __syncthreads();
    }
    const int count = bucketCount[b];
    const int base = sm[b] - count;       // exclusive prefix over buckets
    const int node0 = b << 7;
    const int nN = min(128, n - node0);
    if (t < 128) nc[t] = 0;
    __syncthreads();
    const unsigned long long* pb = pairBuf + (size_t)b * CAP;
    for (int i = t; i < count; i += 512) {
        int d = ((int)(pb[i] >> 32)) & 127;
        atomicAdd(&nc[d], 1);
    }
    __syncthreads();
    if (t < 128) sm[t] = nc[t];
    __syncthreads();
    for (int o = 1; o < 128; o <<= 1) {
        int a = 0;
        if (t < 128 && t >= o) a = sm[t - o];
        __syncthreads();
        if (t < 128) sm[t] += a;
        __syncthreads();
    }
    if (t < 128) nb[t] = base + sm[t] - nc[t];   // exclusive per-node base
    __syncthreads();
    if (t < nN) offs[node0 + t] = nb[t];
    if (b == NBUCK - 1 && t == 0) offs[n] = base + count;
    if (t < 128) nc[t] = 0;
    __syncthreads();
    for (int i = t; i < count; i += 512) {
        unsigned long long p = pb[i];
        int d = ((int)(p >> 32)) & 127;
        int r = atomicAdd(&nc[d], 1);
        csr[nb[d] + r] = (int)(p & 0xffffffffu);
    }
}

// ---------------------------------------------------------------------------
// Fused layer, 512 threads / 8 waves / 64 nodes per block.
// Gather: 32 groups x 16 lanes, 2 nodes per group -> swizzled LDS tile.
// GEMM: wave w = rows (w&3)*16, col-half (w>>2). LAYER2 adds head pass.
// ---------------------------------------------------------------------------
__device__ inline void accum8(float* a, uint4 v) {
    unsigned w;
    w = v.x; a[0] += b2f((unsigned short)(w & 0xffff)); a[1] += b2f((unsigned short)(w >> 16));
    w = v.y; a[2] += b2f((unsigned short)(w & 0xffff)); a[3] += b2f((unsigned short)(w >> 16));
    w = v.z; a[4] += b2f((unsigned short)(w & 0xffff)); a[5] += b2f((unsigned short)(w >> 16));
    w = v.w; a[6] += b2f((unsigned short)(w & 0xffff)); a[7] += b2f((unsigned short)(w >> 16));
}

template<bool LAYER2>
__global__ __launch_bounds__(512, 6) void fused_layer(
        const unsigned short* __restrict__ feat,      // gather source == A2
        const int* __restrict__ offs, const int* __restrict__ csr,
        const unsigned short* __restrict__ Bl, const unsigned short* __restrict__ Br,
        const float* __restrict__ bias,
        const unsigned short* __restrict__ W3, const float* __restrict__ b3,
        void* __restrict__ outP, int n) {
    __shared__ char lds[64 * 256];
    const int t = threadIdx.x;
    const int n0 = blockIdx.x * 64;

    // ---- phase 1: mean-aggregate 64 nodes into LDS (bf16, swizzled) ----
    {
        const int g = t >> 4, l = t & 15;
#pragma unroll
        for (int i = 0; i < 2; ++i) {
            int node = n0 + g * 2 + i;
            if (node < n) {
                int beg = offs[node], end = offs[node + 1];
                int deg = end - beg;
                float acc[8] = {};
                for (int cb = 0; cb < deg; cb += 16) {
                    int rem = deg - cb; if (rem > 16) rem = 16;
                    int e = (cb + l < deg) ? csr[beg + cb + l] : 0;
                    int j = 0;
                    for (; j + 3 < rem; j += 4) {
                        int s0 = __shfl(e, j, 16);
                        int s1 = __shfl(e, j + 1, 16);
                        int s2 = __shfl(e, j + 2, 16);
                        int s3 = __shfl(e, j + 3, 16);
                        uint4 v0 = *reinterpret_cast<const uint4*>(feat + (size_t)s0 * 128 + l * 8);
                        uint4 v1 = *reinterpret_cast<const uint4*>(feat + (size_t)s1 * 128 + l * 8);
                        uint4 v2 = *reinterpret_cast<const uint4*>(feat + (size_t)s2 * 128 + l * 8);
                        uint4 v3 = *reinterpret_cast<const uint4*>(feat + (size_t)s3 * 128 + l * 8);
                        accum8(acc, v0); accum8(acc, v1); accum8(acc, v2); accum8(acc, v3);
                    }
                    for (; j < rem; ++j) {
                        int s0 = __shfl(e, j, 16);
                        uint4 v0 = *reinterpret_cast<const uint4*>(feat + (size_t)s0 * 128 + l * 8);
                        accum8(acc, v0);
                    }
                }
                float inv = deg > 0 ? 1.f / (float)deg : 0.f;
                uint4 o;
                o.x = (unsigned)f2b(acc[0] * inv) | ((unsigned)f2b(acc[1] * inv) << 16);
                o.y = (unsigned)f2b(acc[2] * inv) | ((unsigned)f2b(acc[3] * inv) << 16);
                o.z = (unsigned)f2b(acc[4] * inv) | ((unsigned)f2b(acc[5] * inv) << 16);
                o.w = (unsigned)f2b(acc[6] * inv) | ((unsigned)f2b(acc[7] * inv) << 16);
                int r = node - n0;
                int off = (r * 256 + l * 16) ^ ((r & 7) << 4);
                *reinterpret_cast<uint4*>(lds + off) = o;
            }
        }
    }
    __syncthreads();

    // ---- phase 2: C = relu(mean @ Bl^T + feat @ Br^T + bias) ----
    const int lane = t & 63, wv = t >> 6;
    const int fr = lane & 15, fq = lane >> 4;
    const int wrow = (wv & 3) * 16;      // row block of this wave
    const int ch = wv >> 2;              // column half (0 or 1)
    const int rl = wrow + fr;            // block-local A row for fragments

    f32x4 acc[4];
#pragma unroll
    for (int j = 0; j < 4; ++j) acc[j] = (f32x4){0.f, 0.f, 0.f, 0.f};

    bf16x8 a1[4], a2[4];
#pragma unroll
    for (int ks = 0; ks < 4; ++ks) {
        int off = (rl * 256 + ks * 64 + fq * 16) ^ ((rl & 7) << 4);
        a1[ks] = *reinterpret_cast<const bf16x8*>(lds + off);
    }
    {
        int gr = n0 + rl; gr = gr < n ? gr : n - 1;
        const unsigned short* p = feat + (size_t)gr * 128 + fq * 8;
#pragma unroll
        for (int ks = 0; ks < 4; ++ks)
            a2[ks] = *reinterpret_cast<const bf16x8*>(p + ks * 32);
    }
#pragma unroll
    for (int nt = 0; nt < 4; ++nt) {
        int bcol = ch * 64 + nt * 16 + fr;
        const unsigned short* ql = Bl + (size_t)bcol * 128 + fq * 8;
        const unsigned short* qr = Br + (size_t)bcol * 128 + fq * 8;
#pragma unroll
        for (int ks = 0; ks < 4; ++ks) {
            bf16x8 bl = *reinterpret_cast<const bf16x8*>(ql + ks * 32);
            acc[nt] = __builtin_amdgcn_mfma_f32_16x16x32_bf16(a1[ks], bl, acc[nt], 0, 0, 0);
        }
#pragma unroll
        for (int ks = 0; ks < 4; ++ks) {
            bf16x8 br = *reinterpret_cast<const bf16x8*>(qr + ks * 32);
            acc[nt] = __builtin_amdgcn_mfma_f32_16x16x32_bf16(a2[ks], br, acc[nt], 0, 0, 0);
        }
    }

    if (!LAYER2) {
        unsigned short* h1 = (unsigned short*)outP;
#pragma unroll
        for (int i = 0; i < 4; ++i) {
            int gm = n0 + wrow + fq * 4 + i;
            if (gm >= n) continue;
#pragma unroll
            for (int nt = 0; nt < 4; ++nt) {
                int c = ch * 64 + nt * 16 + fr;
                float v = acc[nt][i] + bias[c];
                h1[(size_t)gm * 128 + c] = f2b(v > 0.f ? v : 0.f);
            }
        }
    } else {
        __syncthreads();   // all waves done reading the mean tile
#pragma unroll
        for (int i = 0; i < 4; ++i) {
            int rL = wrow + fq * 4 + i;
#pragma unroll
            for (int nt = 0; nt < 4; ++nt) {
                int c = ch * 64 + nt * 16 + fr;
                float v = acc[nt][i] + bias[c];
                int off = (rL * 256 + c * 2) ^ ((rL & 7) << 4);
                *reinterpret_cast<unsigned short*>(lds + off) = f2b(v > 0.f ? v : 0.f);
            }
        }
        __syncthreads();
        // ---- phase 3: out = relu(h2 @ W3^T + b3), 64 cols, f32 ----
        f32x4 acc3[2];
#pragma unroll
        for (int j = 0; j < 2; ++j) acc3[j] = (f32x4){0.f, 0.f, 0.f, 0.f};
        bf16x8 a3[4];
#pragma unroll
        for (int ks = 0; ks < 4; ++ks) {
            int off = (rl * 256 + ks * 64 + fq * 16) ^ ((rl & 7) << 4);
            a3[ks] = *reinterpret_cast<const bf16x8*>(lds + off);
        }
#pragma unroll
        for (int nt = 0; nt < 2; ++nt) {
            int wcol = ch * 32 + nt * 16 + fr;
            const unsigned short* q = W3 + (size_t)wcol * 128 + fq * 8;
#pragma unroll
            for (int ks = 0; ks < 4; ++ks) {
                bf16x8 bw = *reinterpret_cast<const bf16x8*>(q + ks * 32);
                acc3[nt] = __builtin_amdgcn_mfma_f32_16x16x32_bf16(a3[ks], bw, acc3[nt], 0, 0, 0);
            }
        }
        float* out = (float*)outP;
#pragma unroll
        for (int i = 0; i < 4; ++i) {
            int gm = n0 + wrow + fq * 4 + i;
            if (gm >= n) continue;
#pragma unroll
            for (int nt = 0; nt < 2; ++nt) {
                int c = ch * 32 + nt * 16 + fr;
                float v = acc3[nt][i] + b3[c];
                out[(size_t)gm * 64 + c] = v > 0.f ? v : 0.f;
            }
        }
    }
}

// ---------------------------------------------------------------------------
extern "C" void kernel_launch(void* const* d_in, const int* in_sizes, int n_in,
                              void* d_out, int out_size, void* d_ws, size_t ws_size,
                              hipStream_t stream) {
    const float* x   = (const float*)d_in[0];
    const int*   ei  = (const int*)d_in[1];
    const float* W1l = (const float*)d_in[2];
    const float* b1l = (const float*)d_in[3];
    const float* W1r = (const float*)d_in[4];
    const float* W2l = (const float*)d_in[5];
    const float* b2l = (const float*)d_in[6];
    const float* W2r = (const float*)d_in[7];
    const float* W3  = (const float*)d_in[8];
    const float* b3  = (const float*)d_in[9];
    float* out = (float*)d_out;

    const int NN = N_NODES, E = N_EDGES;

    char* base = (char*)d_ws;
    unsigned short* xb   = (unsigned short*)(base + 0);         // 12,800,000
    unsigned short* h1b  = (unsigned short*)(base + 12800000);  // 12,800,000
    unsigned short* w1lb = (unsigned short*)(base + 25600000);
    unsigned short* w1rb = (unsigned short*)(base + 25632768);
    unsigned short* w2lb = (unsigned short*)(base + 25665536);
    unsigned short* w2rb = (unsigned short*)(base + 25698304);
    unsigned short* w3b  = (unsigned short*)(base + 25731072);  // 16,384
    int* offs            = (int*)(base + 25747456);             // 200,064
    int* bucketCount     = (int*)(base + 25947520);             // 1,600
    int* csr             = (int*)(base + 25949120);             // 3,200,000
    unsigned long long* pairBuf = (unsigned long long*)(base + 29149128); // 12,812,288

    hipMemsetAsync(bucketCount, 0, 1600, stream);

    const int PREP_ITEMS = XITEMS + WITEMS;   // 1,618,432
    prep<<<(PREP_ITEMS + 255) / 256, 256, 0, stream>>>(
        x, xb, W1l, W1r, W2l, W2r, W3, w1lb, w1rb, w2lb, w2rb, w3b);

    scatter_pairs<<<(E + PB_EDGES - 1) / PB_EDGES, 512, 0, stream>>>(ei, bucketCount, pairBuf, E);
    csr_sort<<<NBUCK, 512, 0, stream>>>(pairBuf, bucketCount, offs, csr, NN);

    const int FB = (NN + 63) / 64;   // 782

    fused_layer<false><<<FB, 512, 0, stream>>>(
        xb, offs, csr, w1lb, w1rb, b1l, nullptr, nullptr, h1b, NN);

    fused_layer<true><<<FB, 512, 0, stream>>>(
        h1b, offs, csr, w2lb, w2rb, b2l, w3b, b3, out, NN);
}

// Round 8
// 163.280 us; speedup vs baseline: 2.8560x; 1.0368x over previous
//
#include <hip/hip_runtime.h>
#include <hip/hip_bf16.h>

#define N_NODES 50000
#define N_EDGES 800000
#define NBUCK 391          // ceil(50000/128) buckets of 128 dst nodes
#define CAP 4096           // pairBuf slots per bucket (expected 2046, >>6 sigma)

typedef short bf16x8 __attribute__((ext_vector_type(8)));
typedef float f32x4 __attribute__((ext_vector_type(4)));
typedef float floatx2 __attribute__((ext_vector_type(2)));

__device__ inline unsigned short f2b(float f) {
    union { float f; unsigned u; } v; v.f = f;
    unsigned r = v.u + 0x7FFF + ((v.u >> 16) & 1);   // RNE
    return (unsigned short)(r >> 16);
}
__device__ inline float b2f(unsigned short u) {
    union { unsigned u; float f; } v; v.u = ((unsigned)u) << 16; return v.f;
}

// ---------------------------------------------------------------------------
// prep: x -> bf16 + fp8, weights -> bf16. Pure copy, no atomics.
// ---------------------------------------------------------------------------
#define XITEMS 1600000   // N_NODES*128/4
#define WITEMS 18432     // 73728/4

__global__ __launch_bounds__(256) void prep(
        const float* __restrict__ x, unsigned short* __restrict__ xb,
        unsigned char* __restrict__ x8,
        const float* __restrict__ W1l, const float* __restrict__ W1r,
        const float* __restrict__ W2l, const float* __restrict__ W2r,
        const float* __restrict__ W3,
        unsigned short* __restrict__ w1lb, unsigned short* __restrict__ w1rb,
        unsigned short* __restrict__ w2lb, unsigned short* __restrict__ w2rb,
        unsigned short* __restrict__ w3b) {
    int gid = blockIdx.x * 256 + threadIdx.x;
    if (gid < XITEMS) {
        int idx = gid * 4;
        float4 v = *reinterpret_cast<const float4*>(x + idx);
        ushort4 o;
        o.x = f2b(v.x); o.y = f2b(v.y); o.z = f2b(v.z); o.w = f2b(v.w);
        *reinterpret_cast<ushort4*>(xb + idx) = o;
        unsigned r = __builtin_amdgcn_cvt_pk_fp8_f32(v.x, v.y, 0, false);
        r = __builtin_amdgcn_cvt_pk_fp8_f32(v.z, v.w, r, true);
        *reinterpret_cast<unsigned*>(x8 + idx) = r;
        return;
    }
    gid -= XITEMS;
    if (gid < WITEMS) {
        int idx = gid * 4;
        const float* s; unsigned short* o; int base;
        if      (idx < 16384) { s = W1l; o = w1lb; base = 0; }
        else if (idx < 32768) { s = W1r; o = w1rb; base = 16384; }
        else if (idx < 49152) { s = W2l; o = w2lb; base = 32768; }
        else if (idx < 65536) { s = W2r; o = w2rb; base = 49152; }
        else                  { s = W3;  o = w3b;  base = 65536; }
        int k = idx - base;
        float4 v = *reinterpret_cast<const float4*>(s + k);
        ushort4 w;
        w.x = f2b(v.x); w.y = f2b(v.y); w.z = f2b(v.z); w.w = f2b(v.w);
        *reinterpret_cast<ushort4*>(o + k) = w;
    }
}

// ---------------------------------------------------------------------------
// h1 bf16 -> fp8 copy (for layer-2 gather)
// ---------------------------------------------------------------------------
__global__ __launch_bounds__(256) void cvt8(const unsigned short* __restrict__ src,
                                            unsigned char* __restrict__ dst, int n) {
    int idx = (blockIdx.x * 256 + threadIdx.x) * 8;
    if (idx >= n) return;
    uint4 v = *reinterpret_cast<const uint4*>(src + idx);
    float f0 = b2f((unsigned short)(v.x & 0xffff)), f1 = b2f((unsigned short)(v.x >> 16));
    float f2 = b2f((unsigned short)(v.y & 0xffff)), f3 = b2f((unsigned short)(v.y >> 16));
    float f4 = b2f((unsigned short)(v.z & 0xffff)), f5 = b2f((unsigned short)(v.z >> 16));
    float f6 = b2f((unsigned short)(v.w & 0xffff)), f7 = b2f((unsigned short)(v.w >> 16));
    uint2 o;
    o.x = __builtin_amdgcn_cvt_pk_fp8_f32(f0, f1, 0, false);
    o.x = __builtin_amdgcn_cvt_pk_fp8_f32(f2, f3, o.x, true);
    o.y = __builtin_amdgcn_cvt_pk_fp8_f32(f4, f5, 0, false);
    o.y = __builtin_amdgcn_cvt_pk_fp8_f32(f6, f7, o.y, true);
    *reinterpret_cast<uint2*>(dst + idx) = o;
}

// ---------------------------------------------------------------------------
// CSR pass 1: partition edges into fixed-capacity bucket regions.
// ---------------------------------------------------------------------------
#define PB_EDGES 4096
__global__ __launch_bounds__(512) void scatter_pairs(
        const int* __restrict__ ei, int* __restrict__ bucketCount,
        unsigned long long* __restrict__ pairBuf, int E) {
    __shared__ int hist[NBUCK];
    __shared__ int gbase[NBUCK];
    const int t = threadIdx.x;
    for (int i = t; i < NBUCK; i += 512) hist[i] = 0;
    __syncthreads();
    const int base = blockIdx.x * PB_EDGES;
    int srcv[8], dstv[8], lr[8], bk[8];
#pragma unroll
    for (int j = 0; j < 8; ++j) {
        int idx = base + j * 512 + t;
        if (idx < E) {
            srcv[j] = ei[idx];
            dstv[j] = ei[E + idx];
            bk[j] = dstv[j] >> 7;
            lr[j] = atomicAdd(&hist[bk[j]], 1);
        } else {
            bk[j] = -1; srcv[j] = 0; dstv[j] = 0; lr[j] = 0;
        }
    }
    __syncthreads();
    for (int i = t; i < NBUCK; i += 512) {
        int h = hist[i];
        if (h) gbase[i] = i * CAP + atomicAdd(&bucketCount[i], h);
    }
    __syncthreads();
#pragma unroll
    for (int j = 0; j < 8; ++j) {
        if (bk[j] >= 0) {
            int pos = gbase[bk[j]] + lr[j];
            pairBuf[pos] = ((unsigned long long)(unsigned)dstv[j] << 32) | (unsigned)srcv[j];
        }
    }
}

// ---------------------------------------------------------------------------
// CSR pass 2: block per bucket -> offs + csr.
// ---------------------------------------------------------------------------
__global__ __launch_bounds__(512) void csr_sort(
        const unsigned long long* __restrict__ pairBuf,
        const int* __restrict__ bucketCount,
        int* __restrict__ offs, int* __restrict__ csr, int n) {
    __shared__ int sm[512];
    __shared__ int nb[128];
    __shared__ int nc[128];
    const int b = blockIdx.x, t = threadIdx.x;
    int v = (t < NBUCK) ? bucketCount[t] : 0;
    sm[t] = v;
    __syncthreads();
    for (int o = 1; o < 512; o <<= 1) {
        int a = (t >= o) ? sm[t - o] : 0;
        __syncthreads();
        sm[t] += a;
        __syncthreads();
    }
    const int count = bucketCount[b];
    const int base = sm[b] - count;       // exclusive prefix over buckets
    const int node0 = b << 7;
    const int nN = min(128, n - node0);
    if (t < 128) nc[t] = 0;
    __syncthreads();
    const unsigned long long* pb = pairBuf + (size_t)b * CAP;
    for (int i = t; i < count; i += 512) {
        int d = ((int)(pb[i] >> 32)) & 127;
        atomicAdd(&nc[d], 1);
    }
    __syncthreads();
    if (t < 128) sm[t] = nc[t];
    __syncthreads();
    for (int o = 1; o < 128; o <<= 1) {
        int a = 0;
        if (t < 128 && t >= o) a = sm[t - o];
        __syncthreads();
        if (t < 128) sm[t] += a;
        __syncthreads();
    }
    if (t < 128) nb[t] = base + sm[t] - nc[t];   // exclusive per-node base
    __syncthreads();
    if (t < nN) offs[node0 + t] = nb[t];
    if (b == NBUCK - 1 && t == 0) offs[n] = base + count;
    if (t < 128) nc[t] = 0;
    __syncthreads();
    for (int i = t; i < count; i += 512) {
        unsigned long long p = pb[i];
        int d = ((int)(p >> 32)) & 127;
        int r = atomicAdd(&nc[d], 1);
        csr[nb[d] + r] = (int)(p & 0xffffffffu);
    }
}

// ---------------------------------------------------------------------------
// Mean aggregation over fp8 rows (128 B). 16 lanes/node, uint2 (8B) loads,
// unroll x8 -> 64 B/lane in flight. f32 accum, bf16 out.
// ---------------------------------------------------------------------------
__device__ inline void acc8f(float* a, uint2 v) {
    floatx2 p;
    p = __builtin_amdgcn_cvt_pk_f32_fp8(v.x, false); a[0] += p.x; a[1] += p.y;
    p = __builtin_amdgcn_cvt_pk_f32_fp8(v.x, true);  a[2] += p.x; a[3] += p.y;
    p = __builtin_amdgcn_cvt_pk_f32_fp8(v.y, false); a[4] += p.x; a[5] += p.y;
    p = __builtin_amdgcn_cvt_pk_f32_fp8(v.y, true);  a[6] += p.x; a[7] += p.y;
}

__global__ __launch_bounds__(256, 8) void aggregate_fp8(
        const unsigned char* __restrict__ feat8, const int* __restrict__ offs,
        const int* __restrict__ csr, unsigned short* __restrict__ out, int n) {
    int grp = (blockIdx.x * 256 + threadIdx.x) >> 4;
    int l = threadIdx.x & 15;
    if (grp >= n) return;
    int beg = offs[grp], end = offs[grp + 1];
    int deg = end - beg;
    float acc[8] = {};
    for (int cb = 0; cb < deg; cb += 16) {
        int rem = deg - cb; if (rem > 16) rem = 16;
        int e = (cb + l < deg) ? csr[beg + cb + l] : 0;
        int j = 0;
        for (; j + 7 < rem; j += 8) {
            uint2 v[8];
#pragma unroll
            for (int k = 0; k < 8; ++k) {
                int s = __shfl(e, j + k, 16);
                v[k] = *reinterpret_cast<const uint2*>(feat8 + (size_t)s * 128 + l * 8);
            }
#pragma unroll
            for (int k = 0; k < 8; ++k) acc8f(acc, v[k]);
        }
        for (; j < rem; ++j) {
            int s = __shfl(e, j, 16);
            uint2 v = *reinterpret_cast<const uint2*>(feat8 + (size_t)s * 128 + l * 8);
            acc8f(acc, v);
        }
    }
    float inv = deg > 0 ? 1.f / (float)deg : 0.f;
    uint4 o;
    o.x = (unsigned)f2b(acc[0] * inv) | ((unsigned)f2b(acc[1] * inv) << 16);
    o.y = (unsigned)f2b(acc[2] * inv) | ((unsigned)f2b(acc[3] * inv) << 16);
    o.z = (unsigned)f2b(acc[4] * inv) | ((unsigned)f2b(acc[5] * inv) << 16);
    o.w = (unsigned)f2b(acc[6] * inv) | ((unsigned)f2b(acc[7] * inv) << 16);
    *reinterpret_cast<uint4*>(out + (size_t)grp * 128 + l * 8) = o;
}

// ---------------------------------------------------------------------------
// Layer GEMM: C[M,128] = relu(A1@B1^T + A2@B2^T + bias), bf16, K=128, no LDS.
// 512 threads = 8 waves x 16 rows, NT=8.
// ---------------------------------------------------------------------------
__global__ __launch_bounds__(512) void gemm_layer(
        const unsigned short* __restrict__ A1, const unsigned short* __restrict__ B1,
        const unsigned short* __restrict__ A2, const unsigned short* __restrict__ B2,
        const float* __restrict__ bias, unsigned short* __restrict__ C, int M) {
    constexpr int K = 128;
    const int lane = threadIdx.x & 63;
    const int wv = threadIdx.x >> 6;
    const int rowBase = blockIdx.x * 128 + wv * 16;
    const int fr = lane & 15;
    const int fq = lane >> 4;

    f32x4 acc[8];
#pragma unroll
    for (int j = 0; j < 8; ++j) acc[j] = (f32x4){0.f, 0.f, 0.f, 0.f};

#pragma unroll
    for (int pass = 0; pass < 2; ++pass) {
        const unsigned short* A = pass ? A2 : A1;
        const unsigned short* B = pass ? B2 : B1;
        bf16x8 af[4];
        {
            int r = rowBase + fr;
            r = r < M ? r : M - 1;
            const unsigned short* p = A + (size_t)r * K + fq * 8;
#pragma unroll
            for (int ks = 0; ks < 4; ++ks)
                af[ks] = *reinterpret_cast<const bf16x8*>(p + ks * 32);
        }
#pragma unroll
        for (int nt = 0; nt < 8; ++nt) {
            const unsigned short* q = B + (size_t)(nt * 16 + fr) * K + fq * 8;
#pragma unroll
            for (int ks = 0; ks < 4; ++ks) {
                bf16x8 bfr = *reinterpret_cast<const bf16x8*>(q + ks * 32);
                acc[nt] = __builtin_amdgcn_mfma_f32_16x16x32_bf16(af[ks], bfr, acc[nt], 0, 0, 0);
            }
        }
    }

#pragma unroll
    for (int i = 0; i < 4; ++i) {
        int gm = rowBase + fq * 4 + i;
        if (gm >= M) continue;
#pragma unroll
        for (int nt = 0; nt < 8; ++nt) {
            int c = nt * 16 + fr;
            float v = acc[nt][i] + bias[c];
            C[(size_t)gm * 128 + c] = f2b(v > 0.f ? v : 0.f);
        }
    }
}

// ---------------------------------------------------------------------------
// Layer-2 GEMM + head: h2 = relu(A1@B1^T + A2@B2^T + bias) -> LDS (swizzled)
// -> out = relu(h2 @ W3^T + b3), f32. 512 threads, 128 rows/block.
// ---------------------------------------------------------------------------
__global__ __launch_bounds__(512) void gemm2_head(
        const unsigned short* __restrict__ A1, const unsigned short* __restrict__ B1,
        const unsigned short* __restrict__ A2, const unsigned short* __restrict__ B2,
        const float* __restrict__ bias,
        const unsigned short* __restrict__ W3, const float* __restrict__ b3,
        float* __restrict__ out, int M) {
    __shared__ char lds[128 * 256];
    constexpr int K = 128;
    const int lane = threadIdx.x & 63;
    const int wv = threadIdx.x >> 6;
    const int rowBase = blockIdx.x * 128 + wv * 16;
    const int fr = lane & 15;
    const int fq = lane >> 4;

    f32x4 acc[8];
#pragma unroll
    for (int j = 0; j < 8; ++j) acc[j] = (f32x4){0.f, 0.f, 0.f, 0.f};

#pragma unroll
    for (int pass = 0; pass < 2; ++pass) {
        const unsigned short* A = pass ? A2 : A1;
        const unsigned short* B = pass ? B2 : B1;
        bf16x8 af[4];
        {
            int r = rowBase + fr;
            r = r < M ? r : M - 1;
            const unsigned short* p = A + (size_t)r * K + fq * 8;
#pragma unroll
            for (int ks = 0; ks < 4; ++ks)
                af[ks] = *reinterpret_cast<const bf16x8*>(p + ks * 32);
        }
#pragma unroll
        for (int nt = 0; nt < 8; ++nt) {
            const unsigned short* q = B + (size_t)(nt * 16 + fr) * K + fq * 8;
#pragma unroll
            for (int ks = 0; ks < 4; ++ks) {
                bf16x8 bfr = *reinterpret_cast<const bf16x8*>(q + ks * 32);
                acc[nt] = __builtin_amdgcn_mfma_f32_16x16x32_bf16(af[ks], bfr, acc[nt], 0, 0, 0);
            }
        }
    }

    // h2 -> LDS, bf16, XOR-swizzled rows
#pragma unroll
    for (int i = 0; i < 4; ++i) {
        int rL = wv * 16 + fq * 4 + i;
#pragma unroll
        for (int nt = 0; nt < 8; ++nt) {
            int c = nt * 16 + fr;
            float v = acc[nt][i] + bias[c];
            int off = (rL * 256 + c * 2) ^ ((rL & 7) << 4);
            *reinterpret_cast<unsigned short*>(lds + off) = f2b(v > 0.f ? v : 0.f);
        }
    }
    __syncthreads();

    // head: out = relu(h2 @ W3^T + b3), 64 cols
    f32x4 acc3[4];
#pragma unroll
    for (int j = 0; j < 4; ++j) acc3[j] = (f32x4){0.f, 0.f, 0.f, 0.f};
    const int rl = wv * 16 + fr;
    bf16x8 a3[4];
#pragma unroll
    for (int ks = 0; ks < 4; ++ks) {
        int off = (rl * 256 + ks * 64 + fq * 16) ^ ((rl & 7) << 4);
        a3[ks] = *reinterpret_cast<const bf16x8*>(lds + off);
    }
#pragma unroll
    for (int nt = 0; nt < 4; ++nt) {
        const unsigned short* q = W3 + (size_t)(nt * 16 + fr) * K + fq * 8;
#pragma unroll
        for (int ks = 0; ks < 4; ++ks) {
            bf16x8 bw = *reinterpret_cast<const bf16x8*>(q + ks * 32);
            acc3[nt] = __builtin_amdgcn_mfma_f32_16x16x32_bf16(a3[ks], bw, acc3[nt], 0, 0, 0);
        }
    }
#pragma unroll
    for (int i = 0; i < 4; ++i) {
        int gm = rowBase + fq * 4 + i;
        if (gm >= M) continue;
#pragma unroll
        for (int nt = 0; nt < 4; ++nt) {
            int c = nt * 16 + fr;
            float v = acc3[nt][i] + b3[c];
            out[(size_t)gm * 64 + c] = v > 0.f ? v : 0.f;
        }
    }
}

// ---------------------------------------------------------------------------
extern "C" void kernel_launch(void* const* d_in, const int* in_sizes, int n_in,
                              void* d_out, int out_size, void* d_ws, size_t ws_size,
                              hipStream_t stream) {
    const float* x   = (const float*)d_in[0];
    const int*   ei  = (const int*)d_in[1];
    const float* W1l = (const float*)d_in[2];
    const float* b1l = (const float*)d_in[3];
    const float* W1r = (const float*)d_in[4];
    const float* W2l = (const float*)d_in[5];
    const float* b2l = (const float*)d_in[6];
    const float* W2r = (const float*)d_in[7];
    const float* W3  = (const float*)d_in[8];
    const float* b3  = (const float*)d_in[9];
    float* out = (float*)d_out;

    const int NN = N_NODES, E = N_EDGES;

    char* base = (char*)d_ws;
    unsigned short* xb    = (unsigned short*)(base + 0);         // 12,800,000
    unsigned short* h1b   = (unsigned short*)(base + 12800000);  // 12,800,000
    unsigned short* meanb = (unsigned short*)(base + 25600000);  // 12,800,000
    unsigned char*  x8    = (unsigned char*) (base + 38400000);  //  6,400,000
    unsigned char*  h18   = (unsigned char*) (base + 44800000);  //  6,400,000
    unsigned short* w1lb  = (unsigned short*)(base + 51200000);
    unsigned short* w1rb  = (unsigned short*)(base + 51232768);
    unsigned short* w2lb  = (unsigned short*)(base + 51265536);
    unsigned short* w2rb  = (unsigned short*)(base + 51298304);
    unsigned short* w3b   = (unsigned short*)(base + 51331072);  // 16,384
    int* offs             = (int*)(base + 51347456);             // 200,064
    int* bucketCount      = (int*)(base + 51547520);             // 1,600
    int* csr              = (int*)(base + 51549120);             // 3,200,000
    unsigned long long* pairBuf = (unsigned long long*)(base + 54749184); // 12,812,288

    hipMemsetAsync(bucketCount, 0, 1600, stream);

    const int PREP_ITEMS = XITEMS + WITEMS;   // 1,618,432
    prep<<<(PREP_ITEMS + 255) / 256, 256, 0, stream>>>(
        x, xb, x8, W1l, W1r, W2l, W2r, W3, w1lb, w1rb, w2lb, w2rb, w3b);

    scatter_pairs<<<(E + PB_EDGES - 1) / PB_EDGES, 512, 0, stream>>>(ei, bucketCount, pairBuf, E);
    csr_sort<<<NBUCK, 512, 0, stream>>>(pairBuf, bucketCount, offs, csr, NN);

    const int AGG_BLK = (NN * 16 + 255) / 256;   // 3125
    const int GB = (NN + 127) / 128;             // 391

    // Layer 1
    aggregate_fp8<<<AGG_BLK, 256, 0, stream>>>(x8, offs, csr, meanb, NN);
    gemm_layer<<<GB, 512, 0, stream>>>(meanb, w1lb, xb, w1rb, b1l, h1b, NN);
    cvt8<<<(NN * 128 / 8 + 255) / 256, 256, 0, stream>>>(h1b, h18, NN * 128);

    // Layer 2 + head
    aggregate_fp8<<<AGG_BLK, 256, 0, stream>>>(h18, offs, csr, meanb, NN);
    gemm2_head<<<GB, 512, 0, stream>>>(meanb, w2lb, h1b, w2rb, b2l, w3b, b3, out, NN);
}

// Round 9
// 155.104 us; speedup vs baseline: 3.0066x; 1.0527x over previous
//
#include <hip/hip_runtime.h>
#include <hip/hip_bf16.h>

#define N_NODES 50000
#define N_EDGES 800000
#define NBUCK 391          // ceil(50000/128) buckets of 128 dst nodes
#define CAP 4096           // pairBuf slots per bucket (expected 2046, >>6 sigma)

typedef short bf16x8 __attribute__((ext_vector_type(8)));
typedef float f32x4 __attribute__((ext_vector_type(4)));
typedef float floatx2 __attribute__((ext_vector_type(2)));

__device__ inline unsigned short f2b(float f) {
    union { float f; unsigned u; } v; v.f = f;
    unsigned r = v.u + 0x7FFF + ((v.u >> 16) & 1);   // RNE
    return (unsigned short)(r >> 16);
}
__device__ inline float b2f(unsigned short u) {
    union { unsigned u; float f; } v; v.u = ((unsigned)u) << 16; return v.f;
}

// ---------------------------------------------------------------------------
// Merged prep + edge partition. Blocks [0,196): scatter edges into
// fixed-capacity bucket regions; blocks [196, ...): cvt x->bf16+fp8, W->bf16.
// ---------------------------------------------------------------------------
#define XITEMS 1600000   // N_NODES*128/4
#define WITEMS 18432     // 73728/4
#define PB_EDGES 4096
#define SCAT_BLKS 196    // ceil(E / PB_EDGES)

__global__ __launch_bounds__(512) void prep_scatter(
        const float* __restrict__ x, unsigned short* __restrict__ xb,
        unsigned char* __restrict__ x8,
        const float* __restrict__ W1l, const float* __restrict__ W1r,
        const float* __restrict__ W2l, const float* __restrict__ W2r,
        const float* __restrict__ W3,
        unsigned short* __restrict__ w1lb, unsigned short* __restrict__ w1rb,
        unsigned short* __restrict__ w2lb, unsigned short* __restrict__ w2rb,
        unsigned short* __restrict__ w3b,
        const int* __restrict__ ei, int* __restrict__ bucketCount,
        unsigned long long* __restrict__ pairBuf) {
    __shared__ int hist[NBUCK];
    __shared__ int gbase[NBUCK];
    const int t = threadIdx.x;

    if (blockIdx.x < SCAT_BLKS) {
        const int E = N_EDGES;
        for (int i = t; i < NBUCK; i += 512) hist[i] = 0;
        __syncthreads();
        const int base = blockIdx.x * PB_EDGES;
        int srcv[8], dstv[8], lr[8], bk[8];
#pragma unroll
        for (int j = 0; j < 8; ++j) {
            int idx = base + j * 512 + t;
            if (idx < E) {
                srcv[j] = ei[idx];
                dstv[j] = ei[E + idx];
                bk[j] = dstv[j] >> 7;
                lr[j] = atomicAdd(&hist[bk[j]], 1);
            } else {
                bk[j] = -1; srcv[j] = 0; dstv[j] = 0; lr[j] = 0;
            }
        }
        __syncthreads();
        for (int i = t; i < NBUCK; i += 512) {
            int h = hist[i];
            if (h) gbase[i] = i * CAP + atomicAdd(&bucketCount[i], h);
        }
        __syncthreads();
#pragma unroll
        for (int j = 0; j < 8; ++j) {
            if (bk[j] >= 0) {
                int pos = gbase[bk[j]] + lr[j];
                pairBuf[pos] = ((unsigned long long)(unsigned)dstv[j] << 32) | (unsigned)srcv[j];
            }
        }
        return;
    }

    int gid = (blockIdx.x - SCAT_BLKS) * 512 + t;
    if (gid < XITEMS) {
        int idx = gid * 4;
        float4 v = *reinterpret_cast<const float4*>(x + idx);
        ushort4 o;
        o.x = f2b(v.x); o.y = f2b(v.y); o.z = f2b(v.z); o.w = f2b(v.w);
        *reinterpret_cast<ushort4*>(xb + idx) = o;
        unsigned r = __builtin_amdgcn_cvt_pk_fp8_f32(v.x, v.y, 0, false);
        r = __builtin_amdgcn_cvt_pk_fp8_f32(v.z, v.w, r, true);
        *reinterpret_cast<unsigned*>(x8 + idx) = r;
        return;
    }
    gid -= XITEMS;
    if (gid < WITEMS) {
        int idx = gid * 4;
        const float* s; unsigned short* o; int base;
        if      (idx < 16384) { s = W1l; o = w1lb; base = 0; }
        else if (idx < 32768) { s = W1r; o = w1rb; base = 16384; }
        else if (idx < 49152) { s = W2l; o = w2lb; base = 32768; }
        else if (idx < 65536) { s = W2r; o = w2rb; base = 49152; }
        else                  { s = W3;  o = w3b;  base = 65536; }
        int k = idx - base;
        float4 v = *reinterpret_cast<const float4*>(s + k);
        ushort4 w;
        w.x = f2b(v.x); w.y = f2b(v.y); w.z = f2b(v.z); w.w = f2b(v.w);
        *reinterpret_cast<ushort4*>(o + k) = w;
    }
}

// ---------------------------------------------------------------------------
// CSR pass 2: block per bucket -> offs + csr.
// ---------------------------------------------------------------------------
__global__ __launch_bounds__(512) void csr_sort(
        const unsigned long long* __restrict__ pairBuf,
        const int* __restrict__ bucketCount,
        int* __restrict__ offs, int* __restrict__ csr, int n) {
    __shared__ int sm[512];
    __shared__ int nb[128];
    __shared__ int nc[128];
    const int b = blockIdx.x, t = threadIdx.x;
    int v = (t < NBUCK) ? bucketCount[t] : 0;
    sm[t] = v;
    __syncthreads();
    for (int o = 1; o < 512; o <<= 1) {
        int a = (t >= o) ? sm[t - o] : 0;
        __syncthreads();
        sm[t] += a;
        __syncthreads();
    }
    const int count = bucketCount[b];
    const int base = sm[b] - count;       // exclusive prefix over buckets
    const int node0 = b << 7;
    const int nN = min(128, n - node0);
    if (t < 128) nc[t] = 0;
    __syncthreads();
    const unsigned long long* pb = pairBuf + (size_t)b * CAP;
    for (int i = t; i < count; i += 512) {
        int d = ((int)(pb[i] >> 32)) & 127;
        atomicAdd(&nc[d], 1);
    }
    __syncthreads();
    if (t < 128) sm[t] = nc[t];
    __syncthreads();
    for (int o = 1; o < 128; o <<= 1) {
        int a = 0;
        if (t < 128 && t >= o) a = sm[t - o];
        __syncthreads();
        if (t < 128) sm[t] += a;
        __syncthreads();
    }
    if (t < 128) nb[t] = base + sm[t] - nc[t];   // exclusive per-node base
    __syncthreads();
    if (t < nN) offs[node0 + t] = nb[t];
    if (b == NBUCK - 1 && t == 0) offs[n] = base + count;
    if (t < 128) nc[t] = 0;
    __syncthreads();
    for (int i = t; i < count; i += 512) {
        unsigned long long p = pb[i];
        int d = ((int)(p >> 32)) & 127;
        int r = atomicAdd(&nc[d], 1);
        csr[nb[d] + r] = (int)(p & 0xffffffffu);
    }
}

// ---------------------------------------------------------------------------
// h1 bf16 -> fp8 copy (for layer-2 gather)
// ---------------------------------------------------------------------------
__global__ __launch_bounds__(256) void cvt8(const unsigned short* __restrict__ src,
                                            unsigned char* __restrict__ dst, int n) {
    int idx = (blockIdx.x * 256 + threadIdx.x) * 8;
    if (idx >= n) return;
    uint4 v = *reinterpret_cast<const uint4*>(src + idx);
    float f0 = b2f((unsigned short)(v.x & 0xffff)), f1 = b2f((unsigned short)(v.x >> 16));
    float f2 = b2f((unsigned short)(v.y & 0xffff)), f3 = b2f((unsigned short)(v.y >> 16));
    float f4 = b2f((unsigned short)(v.z & 0xffff)), f5 = b2f((unsigned short)(v.z >> 16));
    float f6 = b2f((unsigned short)(v.w & 0xffff)), f7 = b2f((unsigned short)(v.w >> 16));
    uint2 o;
    o.x = __builtin_amdgcn_cvt_pk_fp8_f32(f0, f1, 0, false);
    o.x = __builtin_amdgcn_cvt_pk_fp8_f32(f2, f3, o.x, true);
    o.y = __builtin_amdgcn_cvt_pk_fp8_f32(f4, f5, 0, false);
    o.y = __builtin_amdgcn_cvt_pk_fp8_f32(f6, f7, o.y, true);
    *reinterpret_cast<uint2*>(dst + idx) = o;
}

// ---------------------------------------------------------------------------
// Mean aggregation over fp8 rows (128 B). 16 lanes/node, uint2 (8B) loads,
// unroll x8. f32 accum, bf16 out.
// ---------------------------------------------------------------------------
__device__ inline void acc8f(float* a, uint2 v) {
    floatx2 p;
    p = __builtin_amdgcn_cvt_pk_f32_fp8(v.x, false); a[0] += p.x; a[1] += p.y;
    p = __builtin_amdgcn_cvt_pk_f32_fp8(v.x, true);  a[2] += p.x; a[3] += p.y;
    p = __builtin_amdgcn_cvt_pk_f32_fp8(v.y, false); a[4] += p.x; a[5] += p.y;
    p = __builtin_amdgcn_cvt_pk_f32_fp8(v.y, true);  a[6] += p.x; a[7] += p.y;
}

__global__ __launch_bounds__(256, 8) void aggregate_fp8(
        const unsigned char* __restrict__ feat8, const int* __restrict__ offs,
        const int* __restrict__ csr, unsigned short* __restrict__ out, int n) {
    int grp = (blockIdx.x * 256 + threadIdx.x) >> 4;
    int l = threadIdx.x & 15;
    if (grp >= n) return;
    int beg = offs[grp], end = offs[grp + 1];
    int deg = end - beg;
    float acc[8] = {};
    for (int cb = 0; cb < deg; cb += 16) {
        int rem = deg - cb; if (rem > 16) rem = 16;
        int e = (cb + l < deg) ? csr[beg + cb + l] : 0;
        int j = 0;
        for (; j + 7 < rem; j += 8) {
            uint2 v[8];
#pragma unroll
            for (int k = 0; k < 8; ++k) {
                int s = __shfl(e, j + k, 16);
                v[k] = *reinterpret_cast<const uint2*>(feat8 + (size_t)s * 128 + l * 8);
            }
#pragma unroll
            for (int k = 0; k < 8; ++k) acc8f(acc, v[k]);
        }
        for (; j < rem; ++j) {
            int s = __shfl(e, j, 16);
            uint2 v = *reinterpret_cast<const uint2*>(feat8 + (size_t)s * 128 + l * 8);
            acc8f(acc, v);
        }
    }
    float inv = deg > 0 ? 1.f / (float)deg : 0.f;
    uint4 o;
    o.x = (unsigned)f2b(acc[0] * inv) | ((unsigned)f2b(acc[1] * inv) << 16);
    o.y = (unsigned)f2b(acc[2] * inv) | ((unsigned)f2b(acc[3] * inv) << 16);
    o.z = (unsigned)f2b(acc[4] * inv) | ((unsigned)f2b(acc[5] * inv) << 16);
    o.w = (unsigned)f2b(acc[6] * inv) | ((unsigned)f2b(acc[7] * inv) << 16);
    *reinterpret_cast<uint4*>(out + (size_t)grp * 128 + l * 8) = o;
}

// ---------------------------------------------------------------------------
// Layer GEMM: 32 rows / 256 threads / block. Wave w: rows (w&1)*16,
// col-half (w>>1) (NT=4). bf16 MFMA, K=128, no LDS. Grid 1563.
// ---------------------------------------------------------------------------
__global__ __launch_bounds__(256, 8) void gemm_layer(
        const unsigned short* __restrict__ A1, const unsigned short* __restrict__ B1,
        const unsigned short* __restrict__ A2, const unsigned short* __restrict__ B2,
        const float* __restrict__ bias, unsigned short* __restrict__ C, int M) {
    constexpr int K = 128;
    const int lane = threadIdx.x & 63;
    const int wv = threadIdx.x >> 6;
    const int wrow = (wv & 1) * 16;
    const int ch = wv >> 1;
    const int rowBase = blockIdx.x * 32 + wrow;
    const int fr = lane & 15;
    const int fq = lane >> 4;

    f32x4 acc[4];
#pragma unroll
    for (int j = 0; j < 4; ++j) acc[j] = (f32x4){0.f, 0.f, 0.f, 0.f};

#pragma unroll
    for (int pass = 0; pass < 2; ++pass) {
        const unsigned short* A = pass ? A2 : A1;
        const unsigned short* B = pass ? B2 : B1;
        bf16x8 af[4];
        {
            int r = rowBase + fr;
            r = r < M ? r : M - 1;
            const unsigned short* p = A + (size_t)r * K + fq * 8;
#pragma unroll
            for (int ks = 0; ks < 4; ++ks)
                af[ks] = *reinterpret_cast<const bf16x8*>(p + ks * 32);
        }
#pragma unroll
        for (int nt = 0; nt < 4; ++nt) {
            const unsigned short* q = B + (size_t)(ch * 64 + nt * 16 + fr) * K + fq * 8;
#pragma unroll
            for (int ks = 0; ks < 4; ++ks) {
                bf16x8 bfr = *reinterpret_cast<const bf16x8*>(q + ks * 32);
                acc[nt] = __builtin_amdgcn_mfma_f32_16x16x32_bf16(af[ks], bfr, acc[nt], 0, 0, 0);
            }
        }
    }

#pragma unroll
    for (int i = 0; i < 4; ++i) {
        int gm = rowBase + fq * 4 + i;
        if (gm >= M) continue;
#pragma unroll
        for (int nt = 0; nt < 4; ++nt) {
            int c = ch * 64 + nt * 16 + fr;
            float v = acc[nt][i] + bias[c];
            C[(size_t)gm * 128 + c] = f2b(v > 0.f ? v : 0.f);
        }
    }
}

// ---------------------------------------------------------------------------
// Layer-2 GEMM + head, 32 rows / 256 threads. h2 tile -> 8 KB swizzled LDS
// -> head MFMA -> f32 out.
// ---------------------------------------------------------------------------
__global__ __launch_bounds__(256, 8) void gemm2_head(
        const unsigned short* __restrict__ A1, const unsigned short* __restrict__ B1,
        const unsigned short* __restrict__ A2, const unsigned short* __restrict__ B2,
        const float* __restrict__ bias,
        const unsigned short* __restrict__ W3, const float* __restrict__ b3,
        float* __restrict__ out, int M) {
    __shared__ char lds[32 * 256];
    constexpr int K = 128;
    const int lane = threadIdx.x & 63;
    const int wv = threadIdx.x >> 6;
    const int wrow = (wv & 1) * 16;
    const int ch = wv >> 1;
    const int rowBase = blockIdx.x * 32 + wrow;
    const int fr = lane & 15;
    const int fq = lane >> 4;

    f32x4 acc[4];
#pragma unroll
    for (int j = 0; j < 4; ++j) acc[j] = (f32x4){0.f, 0.f, 0.f, 0.f};

#pragma unroll
    for (int pass = 0; pass < 2; ++pass) {
        const unsigned short* A = pass ? A2 : A1;
        const unsigned short* B = pass ? B2 : B1;
        bf16x8 af[4];
        {
            int r = rowBase + fr;
            r = r < M ? r : M - 1;
            const unsigned short* p = A + (size_t)r * K + fq * 8;
#pragma unroll
            for (int ks = 0; ks < 4; ++ks)
                af[ks] = *reinterpret_cast<const bf16x8*>(p + ks * 32);
        }
#pragma unroll
        for (int nt = 0; nt < 4; ++nt) {
            const unsigned short* q = B + (size_t)(ch * 64 + nt * 16 + fr) * K + fq * 8;
#pragma unroll
            for (int ks = 0; ks < 4; ++ks) {
                bf16x8 bfr = *reinterpret_cast<const bf16x8*>(q + ks * 32);
                acc[nt] = __builtin_amdgcn_mfma_f32_16x16x32_bf16(af[ks], bfr, acc[nt], 0, 0, 0);
            }
        }
    }

    // h2 -> LDS, bf16, XOR-swizzled rows (block-local rows 0..31)
#pragma unroll
    for (int i = 0; i < 4; ++i) {
        int rL = wrow + fq * 4 + i;
#pragma unroll
        for (int nt = 0; nt < 4; ++nt) {
            int c = ch * 64 + nt * 16 + fr;
            float v = acc[nt][i] + bias[c];
            int off = (rL * 256 + c * 2) ^ ((rL & 7) << 4);
            *reinterpret_cast<unsigned short*>(lds + off) = f2b(v > 0.f ? v : 0.f);
        }
    }
    __syncthreads();

    // head: out = relu(h2 @ W3^T + b3); wave w: rows (w&1)*16, W3 cols (w>>1)*32
    f32x4 acc3[2];
#pragma unroll
    for (int j = 0; j < 2; ++j) acc3[j] = (f32x4){0.f, 0.f, 0.f, 0.f};
    const int rl = wrow + fr;
    bf16x8 a3[4];
#pragma unroll
    for (int ks = 0; ks < 4; ++ks) {
        int off = (rl * 256 + ks * 64 + fq * 16) ^ ((rl & 7) << 4);
        a3[ks] = *reinterpret_cast<const bf16x8*>(lds + off);
    }
#pragma unroll
    for (int nt = 0; nt < 2; ++nt) {
        int wcol = ch * 32 + nt * 16 + fr;
        const unsigned short* q = W3 + (size_t)wcol * K + fq * 8;
#pragma unroll
        for (int ks = 0; ks < 4; ++ks) {
            bf16x8 bw = *reinterpret_cast<const bf16x8*>(q + ks * 32);
            acc3[nt] = __builtin_amdgcn_mfma_f32_16x16x32_bf16(a3[ks], bw, acc3[nt], 0, 0, 0);
        }
    }
#pragma unroll
    for (int i = 0; i < 4; ++i) {
        int gm = rowBase + fq * 4 + i;
        if (gm >= M) continue;
#pragma unroll
        for (int nt = 0; nt < 2; ++nt) {
            int c = ch * 32 + nt * 16 + fr;
            float v = acc3[nt][i] + b3[c];
            out[(size_t)gm * 64 + c] = v > 0.f ? v : 0.f;
        }
    }
}

// ---------------------------------------------------------------------------
extern "C" void kernel_launch(void* const* d_in, const int* in_sizes, int n_in,
                              void* d_out, int out_size, void* d_ws, size_t ws_size,
                              hipStream_t stream) {
    const float* x   = (const float*)d_in[0];
    const int*   ei  = (const int*)d_in[1];
    const float* W1l = (const float*)d_in[2];
    const float* b1l = (const float*)d_in[3];
    const float* W1r = (const float*)d_in[4];
    const float* W2l = (const float*)d_in[5];
    const float* b2l = (const float*)d_in[6];
    const float* W2r = (const float*)d_in[7];
    const float* W3  = (const float*)d_in[8];
    const float* b3  = (const float*)d_in[9];
    float* out = (float*)d_out;

    const int NN = N_NODES, E = N_EDGES;

    char* base = (char*)d_ws;
    unsigned short* xb    = (unsigned short*)(base + 0);         // 12,800,000
    unsigned short* h1b   = (unsigned short*)(base + 12800000);  // 12,800,000
    unsigned short* meanb = (unsigned short*)(base + 25600000);  // 12,800,000
    unsigned char*  x8    = (unsigned char*) (base + 38400000);  //  6,400,000
    unsigned char*  h18   = (unsigned char*) (base + 44800000);  //  6,400,000
    unsigned short* w1lb  = (unsigned short*)(base + 51200000);
    unsigned short* w1rb  = (unsigned short*)(base + 51232768);
    unsigned short* w2lb  = (unsigned short*)(base + 51265536);
    unsigned short* w2rb  = (unsigned short*)(base + 51298304);
    unsigned short* w3b   = (unsigned short*)(base + 51331072);  // 16,384
    int* offs             = (int*)(base + 51347456);             // 200,064
    int* bucketCount      = (int*)(base + 51547520);             // 1,600
    int* csr              = (int*)(base + 51549120);             // 3,200,000
    unsigned long long* pairBuf = (unsigned long long*)(base + 54749184); // 12,812,288

    hipMemsetAsync(bucketCount, 0, 1600, stream);

    const int PREP_BLKS = (XITEMS + WITEMS + 511) / 512;   // 3161
    prep_scatter<<<SCAT_BLKS + PREP_BLKS, 512, 0, stream>>>(
        x, xb, x8, W1l, W1r, W2l, W2r, W3, w1lb, w1rb, w2lb, w2rb, w3b,
        ei, bucketCount, pairBuf);

    csr_sort<<<NBUCK, 512, 0, stream>>>(pairBuf, bucketCount, offs, csr, NN);

    const int AGG_BLK = (NN * 16 + 255) / 256;   // 3125
    const int GB32 = (NN + 31) / 32;             // 1563

    // Layer 1
    aggregate_fp8<<<AGG_BLK, 256, 0, stream>>>(x8, offs, csr, meanb, NN);
    gemm_layer<<<GB32, 256, 0, stream>>>(meanb, w1lb, xb, w1rb, b1l, h1b, NN);
    cvt8<<<(NN * 128 / 8 + 255) / 256, 256, 0, stream>>>(h1b, h18, NN * 128);

    // Layer 2 + head
    aggregate_fp8<<<AGG_BLK, 256, 0, stream>>>(h18, offs, csr, meanb, NN);
    gemm2_head<<<GB32, 256, 0, stream>>>(meanb, w2lb, h1b, w2rb, b2l, w3b, b3, out, NN);
}

// Round 10
// 128.660 us; speedup vs baseline: 3.6245x; 1.2055x over previous
//
#include <hip/hip_runtime.h>
#include <hip/hip_bf16.h>

#define N_NODES 50000
#define N_PAD 50048        // rows padded so 64-row GEMM tiles can over-read
#define N_EDGES 800000
#define NBUCK 391          // ceil(50000/128) buckets of 128 dst nodes
#define CAP 4096           // pairBuf slots per bucket (expected 2046, >>6 sigma)

typedef short bf16x8 __attribute__((ext_vector_type(8)));
typedef float f32x4 __attribute__((ext_vector_type(4)));
typedef float floatx2 __attribute__((ext_vector_type(2)));

__device__ inline unsigned short f2b(float f) {
    union { float f; unsigned u; } v; v.f = f;
    unsigned r = v.u + 0x7FFF + ((v.u >> 16) & 1);   // RNE
    return (unsigned short)(r >> 16);
}
__device__ inline float b2f(unsigned short u) {
    union { unsigned u; float f; } v; v.u = ((unsigned)u) << 16; return v.f;
}

// ---------------------------------------------------------------------------
// Merged prep + edge partition. Blocks [0,196): scatter edges into
// fixed-capacity bucket regions; blocks [196, ...): cvt x->bf16+fp8, W->bf16.
// ---------------------------------------------------------------------------
#define XITEMS 1600000   // N_NODES*128/4
#define WITEMS 18432     // 73728/4
#define PB_EDGES 4096
#define SCAT_BLKS 196    // ceil(E / PB_EDGES)

__global__ __launch_bounds__(512) void prep_scatter(
        const float* __restrict__ x, unsigned short* __restrict__ xb,
        unsigned char* __restrict__ x8,
        const float* __restrict__ W1l, const float* __restrict__ W1r,
        const float* __restrict__ W2l, const float* __restrict__ W2r,
        const float* __restrict__ W3,
        unsigned short* __restrict__ w1lb, unsigned short* __restrict__ w1rb,
        unsigned short* __restrict__ w2lb, unsigned short* __restrict__ w2rb,
        unsigned short* __restrict__ w3b,
        const int* __restrict__ ei, int* __restrict__ bucketCount,
        unsigned long long* __restrict__ pairBuf) {
    __shared__ int hist[NBUCK];
    __shared__ int gbase[NBUCK];
    const int t = threadIdx.x;

    if (blockIdx.x < SCAT_BLKS) {
        const int E = N_EDGES;
        for (int i = t; i < NBUCK; i += 512) hist[i] = 0;
        __syncthreads();
        const int base = blockIdx.x * PB_EDGES;
        int srcv[8], dstv[8], lr[8], bk[8];
#pragma unroll
        for (int j = 0; j < 8; ++j) {
            int idx = base + j * 512 + t;
            if (idx < E) {
                srcv[j] = ei[idx];
                dstv[j] = ei[E + idx];
                bk[j] = dstv[j] >> 7;
                lr[j] = atomicAdd(&hist[bk[j]], 1);
            } else {
                bk[j] = -1; srcv[j] = 0; dstv[j] = 0; lr[j] = 0;
            }
        }
        __syncthreads();
        for (int i = t; i < NBUCK; i += 512) {
            int h = hist[i];
            if (h) gbase[i] = i * CAP + atomicAdd(&bucketCount[i], h);
        }
        __syncthreads();
#pragma unroll
        for (int j = 0; j < 8; ++j) {
            if (bk[j] >= 0) {
                int pos = gbase[bk[j]] + lr[j];
                pairBuf[pos] = ((unsigned long long)(unsigned)dstv[j] << 32) | (unsigned)srcv[j];
            }
        }
        return;
    }

    int gid = (blockIdx.x - SCAT_BLKS) * 512 + t;
    if (gid < XITEMS) {
        int idx = gid * 4;
        float4 v = *reinterpret_cast<const float4*>(x + idx);
        ushort4 o;
        o.x = f2b(v.x); o.y = f2b(v.y); o.z = f2b(v.z); o.w = f2b(v.w);
        *reinterpret_cast<ushort4*>(xb + idx) = o;
        unsigned r = __builtin_amdgcn_cvt_pk_fp8_f32(v.x, v.y, 0, false);
        r = __builtin_amdgcn_cvt_pk_fp8_f32(v.z, v.w, r, true);
        *reinterpret_cast<unsigned*>(x8 + idx) = r;
        return;
    }
    gid -= XITEMS;
    if (gid < WITEMS) {
        int idx = gid * 4;
        const float* s; unsigned short* o; int base;
        if      (idx < 16384) { s = W1l; o = w1lb; base = 0; }
        else if (idx < 32768) { s = W1r; o = w1rb; base = 16384; }
        else if (idx < 49152) { s = W2l; o = w2lb; base = 32768; }
        else if (idx < 65536) { s = W2r; o = w2rb; base = 49152; }
        else                  { s = W3;  o = w3b;  base = 65536; }
        int k = idx - base;
        float4 v = *reinterpret_cast<const float4*>(s + k);
        ushort4 w;
        w.x = f2b(v.x); w.y = f2b(v.y); w.z = f2b(v.z); w.w = f2b(v.w);
        *reinterpret_cast<ushort4*>(o + k) = w;
    }
}

// ---------------------------------------------------------------------------
// CSR pass 2: block per bucket -> offs + csr.
// ---------------------------------------------------------------------------
__global__ __launch_bounds__(512) void csr_sort(
        const unsigned long long* __restrict__ pairBuf,
        const int* __restrict__ bucketCount,
        int* __restrict__ offs, int* __restrict__ csr, int n) {
    __shared__ int sm[512];
    __shared__ int nb[128];
    __shared__ int nc[128];
    const int b = blockIdx.x, t = threadIdx.x;
    int v = (t < NBUCK) ? bucketCount[t] : 0;
    sm[t] = v;
    __syncthreads();
    for (int o = 1; o < 512; o <<= 1) {
        int a = (t >= o) ? sm[t - o] : 0;
        __syncthreads();
        sm[t] += a;
        __syncthreads();
    }
    const int count = bucketCount[b];
    const int base = sm[b] - count;       // exclusive prefix over buckets
    const int node0 = b << 7;
    const int nN = min(128, n - node0);
    if (t < 128) nc[t] = 0;
    __syncthreads();
    const unsigned long long* pb = pairBuf + (size_t)b * CAP;
    for (int i = t; i < count; i += 512) {
        int d = ((int)(pb[i] >> 32)) & 127;
        atomicAdd(&nc[d], 1);
    }
    __syncthreads();
    if (t < 128) sm[t] = nc[t];
    __syncthreads();
    for (int o = 1; o < 128; o <<= 1) {
        int a = 0;
        if (t < 128 && t >= o) a = sm[t - o];
        __syncthreads();
        if (t < 128) sm[t] += a;
        __syncthreads();
    }
    if (t < 128) nb[t] = base + sm[t] - nc[t];   // exclusive per-node base
    __syncthreads();
    if (t < nN) offs[node0 + t] = nb[t];
    if (b == NBUCK - 1 && t == 0) offs[n] = base + count;
    if (t < 128) nc[t] = 0;
    __syncthreads();
    for (int i = t; i < count; i += 512) {
        unsigned long long p = pb[i];
        int d = ((int)(p >> 32)) & 127;
        int r = atomicAdd(&nc[d], 1);
        csr[nb[d] + r] = (int)(p & 0xffffffffu);
    }
}

// ---------------------------------------------------------------------------
// h1 bf16 -> fp8 copy (for layer-2 gather)
// ---------------------------------------------------------------------------
__global__ __launch_bounds__(256) void cvt8(const unsigned short* __restrict__ src,
                                            unsigned char* __restrict__ dst, int n) {
    int idx = (blockIdx.x * 256 + threadIdx.x) * 8;
    if (idx >= n) return;
    uint4 v = *reinterpret_cast<const uint4*>(src + idx);
    float f0 = b2f((unsigned short)(v.x & 0xffff)), f1 = b2f((unsigned short)(v.x >> 16));
    float f2 = b2f((unsigned short)(v.y & 0xffff)), f3 = b2f((unsigned short)(v.y >> 16));
    float f4 = b2f((unsigned short)(v.z & 0xffff)), f5 = b2f((unsigned short)(v.z >> 16));
    float f6 = b2f((unsigned short)(v.w & 0xffff)), f7 = b2f((unsigned short)(v.w >> 16));
    uint2 o;
    o.x = __builtin_amdgcn_cvt_pk_fp8_f32(f0, f1, 0, false);
    o.x = __builtin_amdgcn_cvt_pk_fp8_f32(f2, f3, o.x, true);
    o.y = __builtin_amdgcn_cvt_pk_fp8_f32(f4, f5, 0, false);
    o.y = __builtin_amdgcn_cvt_pk_fp8_f32(f6, f7, o.y, true);
    *reinterpret_cast<uint2*>(dst + idx) = o;
}

// ---------------------------------------------------------------------------
// Mean aggregation over fp8 rows (128 B). 16 lanes/node, uint2 (8B) loads,
// unroll x8. f32 accum, bf16 out.
// ---------------------------------------------------------------------------
__device__ inline void acc8f(float* a, uint2 v) {
    floatx2 p;
    p = __builtin_amdgcn_cvt_pk_f32_fp8(v.x, false); a[0] += p.x; a[1] += p.y;
    p = __builtin_amdgcn_cvt_pk_f32_fp8(v.x, true);  a[2] += p.x; a[3] += p.y;
    p = __builtin_amdgcn_cvt_pk_f32_fp8(v.y, false); a[4] += p.x; a[5] += p.y;
    p = __builtin_amdgcn_cvt_pk_f32_fp8(v.y, true);  a[6] += p.x; a[7] += p.y;
}

__global__ __launch_bounds__(256, 8) void aggregate_fp8(
        const unsigned char* __restrict__ feat8, const int* __restrict__ offs,
        const int* __restrict__ csr, unsigned short* __restrict__ out, int n) {
    int grp = (blockIdx.x * 256 + threadIdx.x) >> 4;
    int l = threadIdx.x & 15;
    if (grp >= n) return;
    int beg = offs[grp], end = offs[grp + 1];
    int deg = end - beg;
    float acc[8] = {};
    for (int cb = 0; cb < deg; cb += 16) {
        int rem = deg - cb; if (rem > 16) rem = 16;
        int e = (cb + l < deg) ? csr[beg + cb + l] : 0;
        int j = 0;
        for (; j + 7 < rem; j += 8) {
            uint2 v[8];
#pragma unroll
            for (int k = 0; k < 8; ++k) {
                int s = __shfl(e, j + k, 16);
                v[k] = *reinterpret_cast<const uint2*>(feat8 + (size_t)s * 128 + l * 8);
            }
#pragma unroll
            for (int k = 0; k < 8; ++k) acc8f(acc, v[k]);
        }
        for (; j < rem; ++j) {
            int s = __shfl(e, j, 16);
            uint2 v = *reinterpret_cast<const uint2*>(feat8 + (size_t)s * 128 + l * 8);
            acc8f(acc, v);
        }
    }
    float inv = deg > 0 ? 1.f / (float)deg : 0.f;
    uint4 o;
    o.x = (unsigned)f2b(acc[0] * inv) | ((unsigned)f2b(acc[1] * inv) << 16);
    o.y = (unsigned)f2b(acc[2] * inv) | ((unsigned)f2b(acc[3] * inv) << 16);
    o.z = (unsigned)f2b(acc[4] * inv) | ((unsigned)f2b(acc[5] * inv) << 16);
    o.w = (unsigned)f2b(acc[6] * inv) | ((unsigned)f2b(acc[7] * inv) << 16);
    *reinterpret_cast<uint4*>(out + (size_t)grp * 128 + l * 8) = o;
}

// ---------------------------------------------------------------------------
// GEMM v3: 64 rows / 256 threads (4 waves). B (and W3) stationary in VGPRs
// (loaded once per wave); A staged coalesced -> swizzled LDS -> ds_read_b128
// fragments. Wave w: ch = w&1 (64-col half), half = w>>1 (32 rows, 2 tiles).
// HEAD: h2 tile -> LDS (swizzled) -> head MFMA -> f32 out.
// ---------------------------------------------------------------------------
template<bool HEAD>
__global__ __launch_bounds__(256, 2) void gemm_k(
        const unsigned short* __restrict__ A1, const unsigned short* __restrict__ B1,
        const unsigned short* __restrict__ A2, const unsigned short* __restrict__ B2,
        const float* __restrict__ bias,
        const unsigned short* __restrict__ W3, const float* __restrict__ b3,
        void* __restrict__ outP, int M) {
    __shared__ char lds[HEAD ? 49152 : 32768];   // A1 16K | A2 16K | (h2 16K)
    const int t = threadIdx.x;
    const int rowBase = blockIdx.x * 64;
    const int lane = t & 63, wv = t >> 6;
    const int ch = wv & 1, half = wv >> 1;
    const int fr = lane & 15, fq = lane >> 4;
    const int swz = (fr & 7) << 4;

    // ---- issue A staging loads (pre-swizzled source, linear LDS dest) ----
    const char* a1p = (const char*)(A1 + (size_t)rowBase * 128);
    const char* a2p = (const char*)(A2 + (size_t)rowBase * 128);
    uint4 st[8];
#pragma unroll
    for (int c = 0; c < 4; ++c) {
        int q = c * 4096 + t * 16;
        int src = q ^ (((q >> 8) & 7) << 4);
        st[c]     = *reinterpret_cast<const uint4*>(a1p + src);
        st[4 + c] = *reinterpret_cast<const uint4*>(a2p + src);
    }

    // ---- B fragments -> registers (once per wave; overlaps staging) ----
    bf16x8 bl[4][4], br[4][4];
#pragma unroll
    for (int nt = 0; nt < 4; ++nt) {
        const unsigned short* ql = B1 + (size_t)(ch * 64 + nt * 16 + fr) * 128 + fq * 8;
        const unsigned short* qr = B2 + (size_t)(ch * 64 + nt * 16 + fr) * 128 + fq * 8;
#pragma unroll
        for (int ks = 0; ks < 4; ++ks) {
            bl[nt][ks] = *reinterpret_cast<const bf16x8*>(ql + ks * 32);
            br[nt][ks] = *reinterpret_cast<const bf16x8*>(qr + ks * 32);
        }
    }
    bf16x8 w3f[2][4];
    if (HEAD) {
#pragma unroll
        for (int nt = 0; nt < 2; ++nt) {
            const unsigned short* q = W3 + (size_t)(ch * 32 + nt * 16 + fr) * 128 + fq * 8;
#pragma unroll
            for (int ks = 0; ks < 4; ++ks)
                w3f[nt][ks] = *reinterpret_cast<const bf16x8*>(q + ks * 32);
        }
    }

    // ---- write staged A to LDS ----
#pragma unroll
    for (int c = 0; c < 4; ++c) {
        *reinterpret_cast<uint4*>(lds + c * 4096 + t * 16)         = st[c];
        *reinterpret_cast<uint4*>(lds + 16384 + c * 4096 + t * 16) = st[4 + c];
    }
    __syncthreads();

    // ---- main GEMM: 2 row-tiles of 16 per wave ----
#pragma unroll
    for (int tt = 0; tt < 2; ++tt) {
        const int rl = half * 32 + tt * 16 + fr;
        const int rb = rl * 256;
        f32x4 acc[4];
#pragma unroll
        for (int j = 0; j < 4; ++j) acc[j] = (f32x4){0.f, 0.f, 0.f, 0.f};
        bf16x8 a1[4], a2[4];
#pragma unroll
        for (int ks = 0; ks < 4; ++ks) {
            int off = rb + fq * 16 + ks * 64;
            a1[ks] = *reinterpret_cast<const bf16x8*>(lds + (off ^ swz));
            a2[ks] = *reinterpret_cast<const bf16x8*>(lds + 16384 + (off ^ swz));
        }
#pragma unroll
        for (int nt = 0; nt < 4; ++nt)
#pragma unroll
            for (int ks = 0; ks < 4; ++ks) {
                acc[nt] = __builtin_amdgcn_mfma_f32_16x16x32_bf16(a1[ks], bl[nt][ks], acc[nt], 0, 0, 0);
                acc[nt] = __builtin_amdgcn_mfma_f32_16x16x32_bf16(a2[ks], br[nt][ks], acc[nt], 0, 0, 0);
            }
        if (!HEAD) {
            unsigned short* C = (unsigned short*)outP;
#pragma unroll
            for (int i = 0; i < 4; ++i) {
                int gm = rowBase + half * 32 + tt * 16 + fq * 4 + i;
                if (gm >= M) continue;
#pragma unroll
                for (int nt = 0; nt < 4; ++nt) {
                    int c = ch * 64 + nt * 16 + fr;
                    float v = acc[nt][i] + bias[c];
                    C[(size_t)gm * 128 + c] = f2b(v > 0.f ? v : 0.f);
                }
            }
        } else {
#pragma unroll
            for (int i = 0; i < 4; ++i) {
                int rL = half * 32 + tt * 16 + fq * 4 + i;
#pragma unroll
                for (int nt = 0; nt < 4; ++nt) {
                    int c = ch * 64 + nt * 16 + fr;
                    float v = acc[nt][i] + bias[c];
                    int off = (rL * 256 + c * 2) ^ ((rL & 7) << 4);
                    *reinterpret_cast<unsigned short*>(lds + 32768 + off) = f2b(v > 0.f ? v : 0.f);
                }
            }
        }
    }

    if (HEAD) {
        __syncthreads();
        float* out = (float*)outP;
#pragma unroll
        for (int tt = 0; tt < 2; ++tt) {
            const int rl = half * 32 + tt * 16 + fr;
            const int rb = rl * 256;
            bf16x8 a3[4];
#pragma unroll
            for (int ks = 0; ks < 4; ++ks) {
                int off = rb + fq * 16 + ks * 64;
                a3[ks] = *reinterpret_cast<const bf16x8*>(lds + 32768 + (off ^ swz));
            }
            f32x4 acc3[2];
#pragma unroll
            for (int j = 0; j < 2; ++j) acc3[j] = (f32x4){0.f, 0.f, 0.f, 0.f};
#pragma unroll
            for (int nt = 0; nt < 2; ++nt)
#pragma unroll
                for (int ks = 0; ks < 4; ++ks)
                    acc3[nt] = __builtin_amdgcn_mfma_f32_16x16x32_bf16(a3[ks], w3f[nt][ks], acc3[nt], 0, 0, 0);
#pragma unroll
            for (int i = 0; i < 4; ++i) {
                int gm = rowBase + half * 32 + tt * 16 + fq * 4 + i;
                if (gm >= M) continue;
#pragma unroll
                for (int nt = 0; nt < 2; ++nt) {
                    int c = ch * 32 + nt * 16 + fr;
                    float v = acc3[nt][i] + b3[c];
                    out[(size_t)gm * 64 + c] = v > 0.f ? v : 0.f;
                }
            }
        }
    }
}

// ---------------------------------------------------------------------------
extern "C" void kernel_launch(void* const* d_in, const int* in_sizes, int n_in,
                              void* d_out, int out_size, void* d_ws, size_t ws_size,
                              hipStream_t stream) {
    const float* x   = (const float*)d_in[0];
    const int*   ei  = (const int*)d_in[1];
    const float* W1l = (const float*)d_in[2];
    const float* b1l = (const float*)d_in[3];
    const float* W1r = (const float*)d_in[4];
    const float* W2l = (const float*)d_in[5];
    const float* b2l = (const float*)d_in[6];
    const float* W2r = (const float*)d_in[7];
    const float* W3  = (const float*)d_in[8];
    const float* b3  = (const float*)d_in[9];
    float* out = (float*)d_out;

    const int NN = N_NODES, E = N_EDGES;

    char* base = (char*)d_ws;
    // padded feature buffers: N_PAD rows x 256 B = 12,812,288 each
    unsigned short* xb    = (unsigned short*)(base + 0);
    unsigned short* h1b   = (unsigned short*)(base + 12812288);
    unsigned short* meanb = (unsigned short*)(base + 25624576);
    unsigned char*  x8    = (unsigned char*) (base + 38436864);  // 6,400,000
    unsigned char*  h18   = (unsigned char*) (base + 44836864);  // 6,400,000
    unsigned short* w1lb  = (unsigned short*)(base + 51236864);
    unsigned short* w1rb  = (unsigned short*)(base + 51269632);
    unsigned short* w2lb  = (unsigned short*)(base + 51302400);
    unsigned short* w2rb  = (unsigned short*)(base + 51335168);
    unsigned short* w3b   = (unsigned short*)(base + 51367936);  // 16,384
    int* offs             = (int*)(base + 51384320);             // 200,064
    int* bucketCount      = (int*)(base + 51584384);             // 1,600 (+pad)
    int* csr              = (int*)(base + 51586048);             // 3,200,000
    unsigned long long* pairBuf = (unsigned long long*)(base + 54786048); // 12,812,288

    hipMemsetAsync(bucketCount, 0, 1600, stream);

    const int PREP_BLKS = (XITEMS + WITEMS + 511) / 512;   // 3161
    prep_scatter<<<SCAT_BLKS + PREP_BLKS, 512, 0, stream>>>(
        x, xb, x8, W1l, W1r, W2l, W2r, W3, w1lb, w1rb, w2lb, w2rb, w3b,
        ei, bucketCount, pairBuf);

    csr_sort<<<NBUCK, 512, 0, stream>>>(pairBuf, bucketCount, offs, csr, NN);

    const int AGG_BLK = (NN * 16 + 255) / 256;   // 3125
    const int GB64 = (NN + 63) / 64;             // 782

    // Layer 1
    aggregate_fp8<<<AGG_BLK, 256, 0, stream>>>(x8, offs, csr, meanb, NN);
    gemm_k<false><<<GB64, 256, 0, stream>>>(meanb, w1lb, xb, w1rb, b1l,
                                            nullptr, nullptr, h1b, NN);
    cvt8<<<(NN * 128 / 8 + 255) / 256, 256, 0, stream>>>(h1b, h18, NN * 128);

    // Layer 2 + head
    aggregate_fp8<<<AGG_BLK, 256, 0, stream>>>(h18, offs, csr, meanb, NN);
    gemm_k<true><<<GB64, 256, 0, stream>>>(meanb, w2lb, h1b, w2rb, b2l,
                                           w3b, b3, out, NN);
}

// Round 11
// 128.161 us; speedup vs baseline: 3.6386x; 1.0039x over previous
//
#include <hip/hip_runtime.h>
#include <hip/hip_bf16.h>

#define N_NODES 50000
#define N_PAD 50048        // rows padded so 64-row GEMM tiles can over-read
#define N_EDGES 800000
#define NBUCK 391          // ceil(50000/128) buckets of 128 dst nodes
#define CAP 4096           // pairBuf slots per bucket (expected 2046, >>6 sigma)

typedef short bf16x8 __attribute__((ext_vector_type(8)));
typedef float f32x4 __attribute__((ext_vector_type(4)));
typedef float floatx2 __attribute__((ext_vector_type(2)));

__device__ inline unsigned short f2b(float f) {
    union { float f; unsigned u; } v; v.f = f;
    unsigned r = v.u + 0x7FFF + ((v.u >> 16) & 1);   // RNE
    return (unsigned short)(r >> 16);
}
__device__ inline float b2f(unsigned short u) {
    union { unsigned u; float f; } v; v.u = ((unsigned)u) << 16; return v.f;
}

// ---------------------------------------------------------------------------
// Zero the 400-int bucketCount array ourselves: the rocclr fill kernel for
// hipMemsetAsync(1600 B) measured ~41 us/dispatch in-graph (r10 counters).
// ---------------------------------------------------------------------------
__global__ __launch_bounds__(512) void zero_bc(int* __restrict__ bucketCount) {
    int t = threadIdx.x;
    if (t < 400) bucketCount[t] = 0;
}

// ---------------------------------------------------------------------------
// Merged prep + edge partition. Blocks [0,196): scatter edges into
// fixed-capacity bucket regions; blocks [196, ...): cvt x->bf16+fp8, W->bf16.
// ---------------------------------------------------------------------------
#define XITEMS 1600000   // N_NODES*128/4
#define WITEMS 18432     // 73728/4
#define PB_EDGES 4096
#define SCAT_BLKS 196    // ceil(E / PB_EDGES)

__global__ __launch_bounds__(512) void prep_scatter(
        const float* __restrict__ x, unsigned short* __restrict__ xb,
        unsigned char* __restrict__ x8,
        const float* __restrict__ W1l, const float* __restrict__ W1r,
        const float* __restrict__ W2l, const float* __restrict__ W2r,
        const float* __restrict__ W3,
        unsigned short* __restrict__ w1lb, unsigned short* __restrict__ w1rb,
        unsigned short* __restrict__ w2lb, unsigned short* __restrict__ w2rb,
        unsigned short* __restrict__ w3b,
        const int* __restrict__ ei, int* __restrict__ bucketCount,
        unsigned long long* __restrict__ pairBuf) {
    __shared__ int hist[NBUCK];
    __shared__ int gbase[NBUCK];
    const int t = threadIdx.x;

    if (blockIdx.x < SCAT_BLKS) {
        const int E = N_EDGES;
        for (int i = t; i < NBUCK; i += 512) hist[i] = 0;
        __syncthreads();
        const int base = blockIdx.x * PB_EDGES;
        int srcv[8], dstv[8], lr[8], bk[8];
#pragma unroll
        for (int j = 0; j < 8; ++j) {
            int idx = base + j * 512 + t;
            if (idx < E) {
                srcv[j] = ei[idx];
                dstv[j] = ei[E + idx];
                bk[j] = dstv[j] >> 7;
                lr[j] = atomicAdd(&hist[bk[j]], 1);
            } else {
                bk[j] = -1; srcv[j] = 0; dstv[j] = 0; lr[j] = 0;
            }
        }
        __syncthreads();
        for (int i = t; i < NBUCK; i += 512) {
            int h = hist[i];
            if (h) gbase[i] = i * CAP + atomicAdd(&bucketCount[i], h);
        }
        __syncthreads();
#pragma unroll
        for (int j = 0; j < 8; ++j) {
            if (bk[j] >= 0) {
                int pos = gbase[bk[j]] + lr[j];
                pairBuf[pos] = ((unsigned long long)(unsigned)dstv[j] << 32) | (unsigned)srcv[j];
            }
        }
        return;
    }

    int gid = (blockIdx.x - SCAT_BLKS) * 512 + t;
    if (gid < XITEMS) {
        int idx = gid * 4;
        float4 v = *reinterpret_cast<const float4*>(x + idx);
        ushort4 o;
        o.x = f2b(v.x); o.y = f2b(v.y); o.z = f2b(v.z); o.w = f2b(v.w);
        *reinterpret_cast<ushort4*>(xb + idx) = o;
        unsigned r = __builtin_amdgcn_cvt_pk_fp8_f32(v.x, v.y, 0, false);
        r = __builtin_amdgcn_cvt_pk_fp8_f32(v.z, v.w, r, true);
        *reinterpret_cast<unsigned*>(x8 + idx) = r;
        return;
    }
    gid -= XITEMS;
    if (gid < WITEMS) {
        int idx = gid * 4;
        const float* s; unsigned short* o; int base;
        if      (idx < 16384) { s = W1l; o = w1lb; base = 0; }
        else if (idx < 32768) { s = W1r; o = w1rb; base = 16384; }
        else if (idx < 49152) { s = W2l; o = w2lb; base = 32768; }
        else if (idx < 65536) { s = W2r; o = w2rb; base = 49152; }
        else                  { s = W3;  o = w3b;  base = 65536; }
        int k = idx - base;
        float4 v = *reinterpret_cast<const float4*>(s + k);
        ushort4 w;
        w.x = f2b(v.x); w.y = f2b(v.y); w.z = f2b(v.z); w.w = f2b(v.w);
        *reinterpret_cast<ushort4*>(o + k) = w;
    }
}

// ---------------------------------------------------------------------------
// CSR pass 2: block per bucket -> offs + csr.
// ---------------------------------------------------------------------------
__global__ __launch_bounds__(512) void csr_sort(
        const unsigned long long* __restrict__ pairBuf,
        const int* __restrict__ bucketCount,
        int* __restrict__ offs, int* __restrict__ csr, int n) {
    __shared__ int sm[512];
    __shared__ int nb[128];
    __shared__ int nc[128];
    const int b = blockIdx.x, t = threadIdx.x;
    int v = (t < NBUCK) ? bucketCount[t] : 0;
    sm[t] = v;
    __syncthreads();
    for (int o = 1; o < 512; o <<= 1) {
        int a = (t >= o) ? sm[t - o] : 0;
        __syncthreads();
        sm[t] += a;
        __syncthreads();
    }
    const int count = bucketCount[b];
    const int base = sm[b] - count;       // exclusive prefix over buckets
    const int node0 = b << 7;
    const int nN = min(128, n - node0);
    if (t < 128) nc[t] = 0;
    __syncthreads();
    const unsigned long long* pb = pairBuf + (size_t)b * CAP;
    for (int i = t; i < count; i += 512) {
        int d = ((int)(pb[i] >> 32)) & 127;
        atomicAdd(&nc[d], 1);
    }
    __syncthreads();
    if (t < 128) sm[t] = nc[t];
    __syncthreads();
    for (int o = 1; o < 128; o <<= 1) {
        int a = 0;
        if (t < 128 && t >= o) a = sm[t - o];
        __syncthreads();
        if (t < 128) sm[t] += a;
        __syncthreads();
    }
    if (t < 128) nb[t] = base + sm[t] - nc[t];   // exclusive per-node base
    __syncthreads();
    if (t < nN) offs[node0 + t] = nb[t];
    if (b == NBUCK - 1 && t == 0) offs[n] = base + count;
    if (t < 128) nc[t] = 0;
    __syncthreads();
    for (int i = t; i < count; i += 512) {
        unsigned long long p = pb[i];
        int d = ((int)(p >> 32)) & 127;
        int r = atomicAdd(&nc[d], 1);
        csr[nb[d] + r] = (int)(p & 0xffffffffu);
    }
}

// ---------------------------------------------------------------------------
// h1 bf16 -> fp8 copy (for layer-2 gather)
// ---------------------------------------------------------------------------
__global__ __launch_bounds__(256) void cvt8(const unsigned short* __restrict__ src,
                                            unsigned char* __restrict__ dst, int n) {
    int idx = (blockIdx.x * 256 + threadIdx.x) * 8;
    if (idx >= n) return;
    uint4 v = *reinterpret_cast<const uint4*>(src + idx);
    float f0 = b2f((unsigned short)(v.x & 0xffff)), f1 = b2f((unsigned short)(v.x >> 16));
    float f2 = b2f((unsigned short)(v.y & 0xffff)), f3 = b2f((unsigned short)(v.y >> 16));
    float f4 = b2f((unsigned short)(v.z & 0xffff)), f5 = b2f((unsigned short)(v.z >> 16));
    float f6 = b2f((unsigned short)(v.w & 0xffff)), f7 = b2f((unsigned short)(v.w >> 16));
    uint2 o;
    o.x = __builtin_amdgcn_cvt_pk_fp8_f32(f0, f1, 0, false);
    o.x = __builtin_amdgcn_cvt_pk_fp8_f32(f2, f3, o.x, true);
    o.y = __builtin_amdgcn_cvt_pk_fp8_f32(f4, f5, 0, false);
    o.y = __builtin_amdgcn_cvt_pk_fp8_f32(f6, f7, o.y, true);
    *reinterpret_cast<uint2*>(dst + idx) = o;
}

// ---------------------------------------------------------------------------
// Mean aggregation over fp8 rows (128 B). 16 lanes/node, uint2 (8B) loads,
// unroll x8. f32 accum, bf16 out.
// ---------------------------------------------------------------------------
__device__ inline void acc8f(float* a, uint2 v) {
    floatx2 p;
    p = __builtin_amdgcn_cvt_pk_f32_fp8(v.x, false); a[0] += p.x; a[1] += p.y;
    p = __builtin_amdgcn_cvt_pk_f32_fp8(v.x, true);  a[2] += p.x; a[3] += p.y;
    p = __builtin_amdgcn_cvt_pk_f32_fp8(v.y, false); a[4] += p.x; a[5] += p.y;
    p = __builtin_amdgcn_cvt_pk_f32_fp8(v.y, true);  a[6] += p.x; a[7] += p.y;
}

__global__ __launch_bounds__(256, 8) void aggregate_fp8(
        const unsigned char* __restrict__ feat8, const int* __restrict__ offs,
        const int* __restrict__ csr, unsigned short* __restrict__ out, int n) {
    int grp = (blockIdx.x * 256 + threadIdx.x) >> 4;
    int l = threadIdx.x & 15;
    if (grp >= n) return;
    int beg = offs[grp], end = offs[grp + 1];
    int deg = end - beg;
    float acc[8] = {};
    for (int cb = 0; cb < deg; cb += 16) {
        int rem = deg - cb; if (rem > 16) rem = 16;
        int e = (cb + l < deg) ? csr[beg + cb + l] : 0;
        int j = 0;
        for (; j + 7 < rem; j += 8) {
            uint2 v[8];
#pragma unroll
            for (int k = 0; k < 8; ++k) {
                int s = __shfl(e, j + k, 16);
                v[k] = *reinterpret_cast<const uint2*>(feat8 + (size_t)s * 128 + l * 8);
            }
#pragma unroll
            for (int k = 0; k < 8; ++k) acc8f(acc, v[k]);
        }
        for (; j < rem; ++j) {
            int s = __shfl(e, j, 16);
            uint2 v = *reinterpret_cast<const uint2*>(feat8 + (size_t)s * 128 + l * 8);
            acc8f(acc, v);
        }
    }
    float inv = deg > 0 ? 1.f / (float)deg : 0.f;
    uint4 o;
    o.x = (unsigned)f2b(acc[0] * inv) | ((unsigned)f2b(acc[1] * inv) << 16);
    o.y = (unsigned)f2b(acc[2] * inv) | ((unsigned)f2b(acc[3] * inv) << 16);
    o.z = (unsigned)f2b(acc[4] * inv) | ((unsigned)f2b(acc[5] * inv) << 16);
    o.w = (unsigned)f2b(acc[6] * inv) | ((unsigned)f2b(acc[7] * inv) << 16);
    *reinterpret_cast<uint4*>(out + (size_t)grp * 128 + l * 8) = o;
}

// ---------------------------------------------------------------------------
// GEMM v3: 64 rows / 256 threads (4 waves). B (and W3) stationary in VGPRs;
// A staged coalesced -> swizzled LDS -> ds_read_b128 fragments.
// ---------------------------------------------------------------------------
template<bool HEAD>
__global__ __launch_bounds__(256, 2) void gemm_k(
        const unsigned short* __restrict__ A1, const unsigned short* __restrict__ B1,
        const unsigned short* __restrict__ A2, const unsigned short* __restrict__ B2,
        const float* __restrict__ bias,
        const unsigned short* __restrict__ W3, const float* __restrict__ b3,
        void* __restrict__ outP, int M) {
    __shared__ char lds[HEAD ? 49152 : 32768];   // A1 16K | A2 16K | (h2 16K)
    const int t = threadIdx.x;
    const int rowBase = blockIdx.x * 64;
    const int lane = t & 63, wv = t >> 6;
    const int ch = wv & 1, half = wv >> 1;
    const int fr = lane & 15, fq = lane >> 4;
    const int swz = (fr & 7) << 4;

    // ---- issue A staging loads (pre-swizzled source, linear LDS dest) ----
    const char* a1p = (const char*)(A1 + (size_t)rowBase * 128);
    const char* a2p = (const char*)(A2 + (size_t)rowBase * 128);
    uint4 st[8];
#pragma unroll
    for (int c = 0; c < 4; ++c) {
        int q = c * 4096 + t * 16;
        int src = q ^ (((q >> 8) & 7) << 4);
        st[c]     = *reinterpret_cast<const uint4*>(a1p + src);
        st[4 + c] = *reinterpret_cast<const uint4*>(a2p + src);
    }

    // ---- B fragments -> registers (once per wave; overlaps staging) ----
    bf16x8 bl[4][4], br[4][4];
#pragma unroll
    for (int nt = 0; nt < 4; ++nt) {
        const unsigned short* ql = B1 + (size_t)(ch * 64 + nt * 16 + fr) * 128 + fq * 8;
        const unsigned short* qr = B2 + (size_t)(ch * 64 + nt * 16 + fr) * 128 + fq * 8;
#pragma unroll
        for (int ks = 0; ks < 4; ++ks) {
            bl[nt][ks] = *reinterpret_cast<const bf16x8*>(ql + ks * 32);
            br[nt][ks] = *reinterpret_cast<const bf16x8*>(qr + ks * 32);
        }
    }
    bf16x8 w3f[2][4];
    if (HEAD) {
#pragma unroll
        for (int nt = 0; nt < 2; ++nt) {
            const unsigned short* q = W3 + (size_t)(ch * 32 + nt * 16 + fr) * 128 + fq * 8;
#pragma unroll
            for (int ks = 0; ks < 4; ++ks)
                w3f[nt][ks] = *reinterpret_cast<const bf16x8*>(q + ks * 32);
        }
    }

    // ---- write staged A to LDS ----
#pragma unroll
    for (int c = 0; c < 4; ++c) {
        *reinterpret_cast<uint4*>(lds + c * 4096 + t * 16)         = st[c];
        *reinterpret_cast<uint4*>(lds + 16384 + c * 4096 + t * 16) = st[4 + c];
    }
    __syncthreads();

    // ---- main GEMM: 2 row-tiles of 16 per wave ----
#pragma unroll
    for (int tt = 0; tt < 2; ++tt) {
        const int rl = half * 32 + tt * 16 + fr;
        const int rb = rl * 256;
        f32x4 acc[4];
#pragma unroll
        for (int j = 0; j < 4; ++j) acc[j] = (f32x4){0.f, 0.f, 0.f, 0.f};
        bf16x8 a1[4], a2[4];
#pragma unroll
        for (int ks = 0; ks < 4; ++ks) {
            int off = rb + fq * 16 + ks * 64;
            a1[ks] = *reinterpret_cast<const bf16x8*>(lds + (off ^ swz));
            a2[ks] = *reinterpret_cast<const bf16x8*>(lds + 16384 + (off ^ swz));
        }
#pragma unroll
        for (int nt = 0; nt < 4; ++nt)
#pragma unroll
            for (int ks = 0; ks < 4; ++ks) {
                acc[nt] = __builtin_amdgcn_mfma_f32_16x16x32_bf16(a1[ks], bl[nt][ks], acc[nt], 0, 0, 0);
                acc[nt] = __builtin_amdgcn_mfma_f32_16x16x32_bf16(a2[ks], br[nt][ks], acc[nt], 0, 0, 0);
            }
        if (!HEAD) {
            unsigned short* C = (unsigned short*)outP;
#pragma unroll
            for (int i = 0; i < 4; ++i) {
                int gm = rowBase + half * 32 + tt * 16 + fq * 4 + i;
                if (gm >= M) continue;
#pragma unroll
                for (int nt = 0; nt < 4; ++nt) {
                    int c = ch * 64 + nt * 16 + fr;
                    float v = acc[nt][i] + bias[c];
                    C[(size_t)gm * 128 + c] = f2b(v > 0.f ? v : 0.f);
                }
            }
        } else {
#pragma unroll
            for (int i = 0; i < 4; ++i) {
                int rL = half * 32 + tt * 16 + fq * 4 + i;
#pragma unroll
                for (int nt = 0; nt < 4; ++nt) {
                    int c = ch * 64 + nt * 16 + fr;
                    float v = acc[nt][i] + bias[c];
                    int off = (rL * 256 + c * 2) ^ ((rL & 7) << 4);
                    *reinterpret_cast<unsigned short*>(lds + 32768 + off) = f2b(v > 0.f ? v : 0.f);
                }
            }
        }
    }

    if (HEAD) {
        __syncthreads();
        float* out = (float*)outP;
#pragma unroll
        for (int tt = 0; tt < 2; ++tt) {
            const int rl = half * 32 + tt * 16 + fr;
            const int rb = rl * 256;
            bf16x8 a3[4];
#pragma unroll
            for (int ks = 0; ks < 4; ++ks) {
                int off = rb + fq * 16 + ks * 64;
                a3[ks] = *reinterpret_cast<const bf16x8*>(lds + 32768 + (off ^ swz));
            }
            f32x4 acc3[2];
#pragma unroll
            for (int j = 0; j < 2; ++j) acc3[j] = (f32x4){0.f, 0.f, 0.f, 0.f};
#pragma unroll
            for (int nt = 0; nt < 2; ++nt)
#pragma unroll
                for (int ks = 0; ks < 4; ++ks)
                    acc3[nt] = __builtin_amdgcn_mfma_f32_16x16x32_bf16(a3[ks], w3f[nt][ks], acc3[nt], 0, 0, 0);
#pragma unroll
            for (int i = 0; i < 4; ++i) {
                int gm = rowBase + half * 32 + tt * 16 + fq * 4 + i;
                if (gm >= M) continue;
#pragma unroll
                for (int nt = 0; nt < 2; ++nt) {
                    int c = ch * 32 + nt * 16 + fr;
                    float v = acc3[nt][i] + b3[c];
                    out[(size_t)gm * 64 + c] = v > 0.f ? v : 0.f;
                }
            }
        }
    }
}

// ---------------------------------------------------------------------------
extern "C" void kernel_launch(void* const* d_in, const int* in_sizes, int n_in,
                              void* d_out, int out_size, void* d_ws, size_t ws_size,
                              hipStream_t stream) {
    const float* x   = (const float*)d_in[0];
    const int*   ei  = (const int*)d_in[1];
    const float* W1l = (const float*)d_in[2];
    const float* b1l = (const float*)d_in[3];
    const float* W1r = (const float*)d_in[4];
    const float* W2l = (const float*)d_in[5];
    const float* b2l = (const float*)d_in[6];
    const float* W2r = (const float*)d_in[7];
    const float* W3  = (const float*)d_in[8];
    const float* b3  = (const float*)d_in[9];
    float* out = (float*)d_out;

    const int NN = N_NODES, E = N_EDGES;

    char* base = (char*)d_ws;
    // padded feature buffers: N_PAD rows x 256 B = 12,812,288 each
    unsigned short* xb    = (unsigned short*)(base + 0);
    unsigned short* h1b   = (unsigned short*)(base + 12812288);
    unsigned short* meanb = (unsigned short*)(base + 25624576);
    unsigned char*  x8    = (unsigned char*) (base + 38436864);  // 6,400,000
    unsigned char*  h18   = (unsigned char*) (base + 44836864);  // 6,400,000
    unsigned short* w1lb  = (unsigned short*)(base + 51236864);
    unsigned short* w1rb  = (unsigned short*)(base + 51269632);
    unsigned short* w2lb  = (unsigned short*)(base + 51302400);
    unsigned short* w2rb  = (unsigned short*)(base + 51335168);
    unsigned short* w3b   = (unsigned short*)(base + 51367936);  // 16,384
    int* offs             = (int*)(base + 51384320);             // 200,064
    int* bucketCount      = (int*)(base + 51584384);             // 1,600 (+pad)
    int* csr              = (int*)(base + 51586048);             // 3,200,000
    unsigned long long* pairBuf = (unsigned long long*)(base + 54786048); // 12,812,288

    zero_bc<<<1, 512, 0, stream>>>(bucketCount);

    const int PREP_BLKS = (XITEMS + WITEMS + 511) / 512;   // 3161
    prep_scatter<<<SCAT_BLKS + PREP_BLKS, 512, 0, stream>>>(
        x, xb, x8, W1l, W1r, W2l, W2r, W3, w1lb, w1rb, w2lb, w2rb, w3b,
        ei, bucketCount, pairBuf);

    csr_sort<<<NBUCK, 512, 0, stream>>>(pairBuf, bucketCount, offs, csr, NN);

    const int AGG_BLK = (NN * 16 + 255) / 256;   // 3125
    const int GB64 = (NN + 63) / 64;             // 782

    // Layer 1
    aggregate_fp8<<<AGG_BLK, 256, 0, stream>>>(x8, offs, csr, meanb, NN);
    gemm_k<false><<<GB64, 256, 0, stream>>>(meanb, w1lb, xb, w1rb, b1l,
                                            nullptr, nullptr, h1b, NN);
    cvt8<<<(NN * 128 / 8 + 255) / 256, 256, 0, stream>>>(h1b, h18, NN * 128);

    // Layer 2 + head
    aggregate_fp8<<<AGG_BLK, 256, 0, stream>>>(h18, offs, csr, meanb, NN);
    gemm_k<true><<<GB64, 256, 0, stream>>>(meanb, w2lb, h1b, w2rb, b2l,
                                           w3b, b3, out, NN);
}

// Round 12
// 124.566 us; speedup vs baseline: 3.7436x; 1.0289x over previous
//
#include <hip/hip_runtime.h>
#include <hip/hip_bf16.h>

#define N_NODES 50000
#define N_PAD 50048        // rows padded so 64-row GEMM tiles can over-read
#define N_EDGES 800000
#define NBUCK 391          // ceil(50000/128) buckets of 128 dst nodes
#define CAP 4096           // pairBuf slots per bucket (expected 2046, >>6 sigma)

typedef short bf16x8 __attribute__((ext_vector_type(8)));
typedef float f32x4 __attribute__((ext_vector_type(4)));
typedef float floatx2 __attribute__((ext_vector_type(2)));

__device__ inline unsigned short f2b(float f) {
    union { float f; unsigned u; } v; v.f = f;
    unsigned r = v.u + 0x7FFF + ((v.u >> 16) & 1);   // RNE
    return (unsigned short)(r >> 16);
}
__device__ inline float b2f(unsigned short u) {
    union { unsigned u; float f; } v; v.u = ((unsigned)u) << 16; return v.f;
}

// ---------------------------------------------------------------------------
// Zero the 400-int bucketCount array (cheap 1-block kernel; must precede the
// scatter atomics each call since d_ws state must not leak across calls).
// ---------------------------------------------------------------------------
__global__ __launch_bounds__(512) void zero_bc(int* __restrict__ bucketCount) {
    int t = threadIdx.x;
    if (t < 400) bucketCount[t] = 0;
}

// ---------------------------------------------------------------------------
// Merged prep + edge partition. Blocks [0,196): scatter edges into
// fixed-capacity bucket regions; blocks [196, ...): cvt x->bf16+fp8, W->bf16.
// ---------------------------------------------------------------------------
#define XITEMS 1600000   // N_NODES*128/4
#define WITEMS 18432     // 73728/4
#define PB_EDGES 4096
#define SCAT_BLKS 196    // ceil(E / PB_EDGES)

__global__ __launch_bounds__(512) void prep_scatter(
        const float* __restrict__ x, unsigned short* __restrict__ xb,
        unsigned char* __restrict__ x8,
        const float* __restrict__ W1l, const float* __restrict__ W1r,
        const float* __restrict__ W2l, const float* __restrict__ W2r,
        const float* __restrict__ W3,
        unsigned short* __restrict__ w1lb, unsigned short* __restrict__ w1rb,
        unsigned short* __restrict__ w2lb, unsigned short* __restrict__ w2rb,
        unsigned short* __restrict__ w3b,
        const int* __restrict__ ei, int* __restrict__ bucketCount,
        unsigned long long* __restrict__ pairBuf) {
    __shared__ int hist[NBUCK];
    __shared__ int gbase[NBUCK];
    const int t = threadIdx.x;

    if (blockIdx.x < SCAT_BLKS) {
        const int E = N_EDGES;
        for (int i = t; i < NBUCK; i += 512) hist[i] = 0;
        __syncthreads();
        const int base = blockIdx.x * PB_EDGES;
        int srcv[8], dstv[8], lr[8], bk[8];
#pragma unroll
        for (int j = 0; j < 8; ++j) {
            int idx = base + j * 512 + t;
            if (idx < E) {
                srcv[j] = ei[idx];
                dstv[j] = ei[E + idx];
                bk[j] = dstv[j] >> 7;
                lr[j] = atomicAdd(&hist[bk[j]], 1);
            } else {
                bk[j] = -1; srcv[j] = 0; dstv[j] = 0; lr[j] = 0;
            }
        }
        __syncthreads();
        for (int i = t; i < NBUCK; i += 512) {
            int h = hist[i];
            if (h) gbase[i] = i * CAP + atomicAdd(&bucketCount[i], h);
        }
        __syncthreads();
#pragma unroll
        for (int j = 0; j < 8; ++j) {
            if (bk[j] >= 0) {
                int pos = gbase[bk[j]] + lr[j];
                pairBuf[pos] = ((unsigned long long)(unsigned)dstv[j] << 32) | (unsigned)srcv[j];
            }
        }
        return;
    }

    int gid = (blockIdx.x - SCAT_BLKS) * 512 + t;
    if (gid < XITEMS) {
        int idx = gid * 4;
        float4 v = *reinterpret_cast<const float4*>(x + idx);
        ushort4 o;
        o.x = f2b(v.x); o.y = f2b(v.y); o.z = f2b(v.z); o.w = f2b(v.w);
        *reinterpret_cast<ushort4*>(xb + idx) = o;
        unsigned r = __builtin_amdgcn_cvt_pk_fp8_f32(v.x, v.y, 0, false);
        r = __builtin_amdgcn_cvt_pk_fp8_f32(v.z, v.w, r, true);
        *reinterpret_cast<unsigned*>(x8 + idx) = r;
        return;
    }
    gid -= XITEMS;
    if (gid < WITEMS) {
        int idx = gid * 4;
        const float* s; unsigned short* o; int base;
        if      (idx < 16384) { s = W1l; o = w1lb; base = 0; }
        else if (idx < 32768) { s = W1r; o = w1rb; base = 16384; }
        else if (idx < 49152) { s = W2l; o = w2lb; base = 32768; }
        else if (idx < 65536) { s = W2r; o = w2rb; base = 49152; }
        else                  { s = W3;  o = w3b;  base = 65536; }
        int k = idx - base;
        float4 v = *reinterpret_cast<const float4*>(s + k);
        ushort4 w;
        w.x = f2b(v.x); w.y = f2b(v.y); w.z = f2b(v.z); w.w = f2b(v.w);
        *reinterpret_cast<ushort4*>(o + k) = w;
    }
}

// ---------------------------------------------------------------------------
// CSR pass 2: block per bucket -> offs + csr.
// ---------------------------------------------------------------------------
__global__ __launch_bounds__(512) void csr_sort(
        const unsigned long long* __restrict__ pairBuf,
        const int* __restrict__ bucketCount,
        int* __restrict__ offs, int* __restrict__ csr, int n) {
    __shared__ int sm[512];
    __shared__ int nb[128];
    __shared__ int nc[128];
    const int b = blockIdx.x, t = threadIdx.x;
    int v = (t < NBUCK) ? bucketCount[t] : 0;
    sm[t] = v;
    __syncthreads();
    for (int o = 1; o < 512; o <<= 1) {
        int a = (t >= o) ? sm[t - o] : 0;
        __syncthreads();
        sm[t] += a;
        __syncthreads();
    }
    const int count = bucketCount[b];
    const int base = sm[b] - count;       // exclusive prefix over buckets
    const int node0 = b << 7;
    const int nN = min(128, n - node0);
    if (t < 128) nc[t] = 0;
    __syncthreads();
    const unsigned long long* pb = pairBuf + (size_t)b * CAP;
    for (int i = t; i < count; i += 512) {
        int d = ((int)(pb[i] >> 32)) & 127;
        atomicAdd(&nc[d], 1);
    }
    __syncthreads();
    if (t < 128) sm[t] = nc[t];
    __syncthreads();
    for (int o = 1; o < 128; o <<= 1) {
        int a = 0;
        if (t < 128 && t >= o) a = sm[t - o];
        __syncthreads();
        if (t < 128) sm[t] += a;
        __syncthreads();
    }
    if (t < 128) nb[t] = base + sm[t] - nc[t];   // exclusive per-node base
    __syncthreads();
    if (t < nN) offs[node0 + t] = nb[t];
    if (b == NBUCK - 1 && t == 0) offs[n] = base + count;
    if (t < 128) nc[t] = 0;
    __syncthreads();
    for (int i = t; i < count; i += 512) {
        unsigned long long p = pb[i];
        int d = ((int)(p >> 32)) & 127;
        int r = atomicAdd(&nc[d], 1);
        csr[nb[d] + r] = (int)(p & 0xffffffffu);
    }
}

// ---------------------------------------------------------------------------
// Mean aggregation over fp8 rows (128 B). 16 lanes/node, uint2 (8B) loads,
// unroll x8. f32 accum, bf16 out.
// ---------------------------------------------------------------------------
__device__ inline void acc8f(float* a, uint2 v) {
    floatx2 p;
    p = __builtin_amdgcn_cvt_pk_f32_fp8(v.x, false); a[0] += p.x; a[1] += p.y;
    p = __builtin_amdgcn_cvt_pk_f32_fp8(v.x, true);  a[2] += p.x; a[3] += p.y;
    p = __builtin_amdgcn_cvt_pk_f32_fp8(v.y, false); a[4] += p.x; a[5] += p.y;
    p = __builtin_amdgcn_cvt_pk_f32_fp8(v.y, true);  a[6] += p.x; a[7] += p.y;
}

__global__ __launch_bounds__(256, 8) void aggregate_fp8(
        const unsigned char* __restrict__ feat8, const int* __restrict__ offs,
        const int* __restrict__ csr, unsigned short* __restrict__ out, int n) {
    int grp = (blockIdx.x * 256 + threadIdx.x) >> 4;
    int l = threadIdx.x & 15;
    if (grp >= n) return;
    int beg = offs[grp], end = offs[grp + 1];
    int deg = end - beg;
    float acc[8] = {};
    for (int cb = 0; cb < deg; cb += 16) {
        int rem = deg - cb; if (rem > 16) rem = 16;
        int e = (cb + l < deg) ? csr[beg + cb + l] : 0;
        int j = 0;
        for (; j + 7 < rem; j += 8) {
            uint2 v[8];
#pragma unroll
            for (int k = 0; k < 8; ++k) {
                int s = __shfl(e, j + k, 16);
                v[k] = *reinterpret_cast<const uint2*>(feat8 + (size_t)s * 128 + l * 8);
            }
#pragma unroll
            for (int k = 0; k < 8; ++k) acc8f(acc, v[k]);
        }
        for (; j < rem; ++j) {
            int s = __shfl(e, j, 16);
            uint2 v = *reinterpret_cast<const uint2*>(feat8 + (size_t)s * 128 + l * 8);
            acc8f(acc, v);
        }
    }
    float inv = deg > 0 ? 1.f / (float)deg : 0.f;
    uint4 o;
    o.x = (unsigned)f2b(acc[0] * inv) | ((unsigned)f2b(acc[1] * inv) << 16);
    o.y = (unsigned)f2b(acc[2] * inv) | ((unsigned)f2b(acc[3] * inv) << 16);
    o.z = (unsigned)f2b(acc[4] * inv) | ((unsigned)f2b(acc[5] * inv) << 16);
    o.w = (unsigned)f2b(acc[6] * inv) | ((unsigned)f2b(acc[7] * inv) << 16);
    *reinterpret_cast<uint4*>(out + (size_t)grp * 128 + l * 8) = o;
}

// ---------------------------------------------------------------------------
// GEMM v4: 64 rows / 256 threads (4 waves). B (and W3) stationary in VGPRs;
// A staged coalesced -> swizzled LDS -> ds_read_b128 fragments.
// Epilogue routes C through a swizzled LDS tile (both variants):
//  !HEAD: read tile back coalesced, emit h1b (bf16 uint4) + h18 (fp8 uint2)
//   HEAD: tile = h2, second MFMA stage vs W3 -> f32 out.
// LDS: A1 16K | A2 16K | tile 16K = 48 KB.
// ---------------------------------------------------------------------------
template<bool HEAD>
__global__ __launch_bounds__(256, 2) void gemm_k(
        const unsigned short* __restrict__ A1, const unsigned short* __restrict__ B1,
        const unsigned short* __restrict__ A2, const unsigned short* __restrict__ B2,
        const float* __restrict__ bias,
        const unsigned short* __restrict__ W3, const float* __restrict__ b3,
        void* __restrict__ outP, unsigned char* __restrict__ fp8out, int M) {
    __shared__ char lds[49152];
    const int t = threadIdx.x;
    const int rowBase = blockIdx.x * 64;
    const int lane = t & 63, wv = t >> 6;
    const int ch = wv & 1, half = wv >> 1;
    const int fr = lane & 15, fq = lane >> 4;
    const int swz = (fr & 7) << 4;

    // ---- issue A staging loads (pre-swizzled source, linear LDS dest) ----
    const char* a1p = (const char*)(A1 + (size_t)rowBase * 128);
    const char* a2p = (const char*)(A2 + (size_t)rowBase * 128);
    uint4 st[8];
#pragma unroll
    for (int c = 0; c < 4; ++c) {
        int q = c * 4096 + t * 16;
        int src = q ^ (((q >> 8) & 7) << 4);
        st[c]     = *reinterpret_cast<const uint4*>(a1p + src);
        st[4 + c] = *reinterpret_cast<const uint4*>(a2p + src);
    }

    // ---- B fragments -> registers (once per wave; overlaps staging) ----
    bf16x8 bl[4][4], br[4][4];
#pragma unroll
    for (int nt = 0; nt < 4; ++nt) {
        const unsigned short* ql = B1 + (size_t)(ch * 64 + nt * 16 + fr) * 128 + fq * 8;
        const unsigned short* qr = B2 + (size_t)(ch * 64 + nt * 16 + fr) * 128 + fq * 8;
#pragma unroll
        for (int ks = 0; ks < 4; ++ks) {
            bl[nt][ks] = *reinterpret_cast<const bf16x8*>(ql + ks * 32);
            br[nt][ks] = *reinterpret_cast<const bf16x8*>(qr + ks * 32);
        }
    }
    bf16x8 w3f[2][4];
    if (HEAD) {
#pragma unroll
        for (int nt = 0; nt < 2; ++nt) {
            const unsigned short* q = W3 + (size_t)(ch * 32 + nt * 16 + fr) * 128 + fq * 8;
#pragma unroll
            for (int ks = 0; ks < 4; ++ks)
                w3f[nt][ks] = *reinterpret_cast<const bf16x8*>(q + ks * 32);
        }
    }

    // ---- write staged A to LDS ----
#pragma unroll
    for (int c = 0; c < 4; ++c) {
        *reinterpret_cast<uint4*>(lds + c * 4096 + t * 16)         = st[c];
        *reinterpret_cast<uint4*>(lds + 16384 + c * 4096 + t * 16) = st[4 + c];
    }
    __syncthreads();

    // ---- main GEMM: 2 row-tiles of 16 per wave; C -> swizzled LDS tile ----
#pragma unroll
    for (int tt = 0; tt < 2; ++tt) {
        const int rl = half * 32 + tt * 16 + fr;
        const int rb = rl * 256;
        f32x4 acc[4];
#pragma unroll
        for (int j = 0; j < 4; ++j) acc[j] = (f32x4){0.f, 0.f, 0.f, 0.f};
        bf16x8 a1[4], a2[4];
#pragma unroll
        for (int ks = 0; ks < 4; ++ks) {
            int off = rb + fq * 16 + ks * 64;
            a1[ks] = *reinterpret_cast<const bf16x8*>(lds + (off ^ swz));
            a2[ks] = *reinterpret_cast<const bf16x8*>(lds + 16384 + (off ^ swz));
        }
#pragma unroll
        for (int nt = 0; nt < 4; ++nt)
#pragma unroll
            for (int ks = 0; ks < 4; ++ks) {
                acc[nt] = __builtin_amdgcn_mfma_f32_16x16x32_bf16(a1[ks], bl[nt][ks], acc[nt], 0, 0, 0);
                acc[nt] = __builtin_amdgcn_mfma_f32_16x16x32_bf16(a2[ks], br[nt][ks], acc[nt], 0, 0, 0);
            }
#pragma unroll
        for (int i = 0; i < 4; ++i) {
            int rL = half * 32 + tt * 16 + fq * 4 + i;
#pragma unroll
            for (int nt = 0; nt < 4; ++nt) {
                int c = ch * 64 + nt * 16 + fr;
                float v = acc[nt][i] + bias[c];
                int off = (rL * 256 + c * 2) ^ ((rL & 7) << 4);
                *reinterpret_cast<unsigned short*>(lds + 32768 + off) = f2b(v > 0.f ? v : 0.f);
            }
        }
    }
    __syncthreads();

    if (!HEAD) {
        // ---- coalesced readback: h1b (bf16) + h18 (fp8) ----
        unsigned short* C = (unsigned short*)outP;
#pragma unroll
        for (int c4 = 0; c4 < 4; ++c4) {
            int g = c4 * 256 + t;          // chunk id 0..1023
            int rL = g >> 4, k = g & 15;
            int gm = rowBase + rL;
            if (gm >= M) continue;
            int off = (rL * 256 + k * 16) ^ ((rL & 7) << 4);
            uint4 v = *reinterpret_cast<const uint4*>(lds + 32768 + off);
            *reinterpret_cast<uint4*>(C + (size_t)gm * 128 + k * 8) = v;
            float f0 = b2f((unsigned short)(v.x & 0xffff)), f1 = b2f((unsigned short)(v.x >> 16));
            float f2 = b2f((unsigned short)(v.y & 0xffff)), f3 = b2f((unsigned short)(v.y >> 16));
            float f4 = b2f((unsigned short)(v.z & 0xffff)), f5 = b2f((unsigned short)(v.z >> 16));
            float f6 = b2f((unsigned short)(v.w & 0xffff)), f7 = b2f((unsigned short)(v.w >> 16));
            uint2 o;
            o.x = __builtin_amdgcn_cvt_pk_fp8_f32(f0, f1, 0, false);
            o.x = __builtin_amdgcn_cvt_pk_fp8_f32(f2, f3, o.x, true);
            o.y = __builtin_amdgcn_cvt_pk_fp8_f32(f4, f5, 0, false);
            o.y = __builtin_amdgcn_cvt_pk_fp8_f32(f6, f7, o.y, true);
            *reinterpret_cast<uint2*>(fp8out + (size_t)gm * 128 + k * 8) = o;
        }
    } else {
        // ---- head: out = relu(h2 @ W3^T + b3), 64 cols, f32 ----
        float* out = (float*)outP;
#pragma unroll
        for (int tt = 0; tt < 2; ++tt) {
            const int rl = half * 32 + tt * 16 + fr;
            const int rb = rl * 256;
            bf16x8 a3[4];
#pragma unroll
            for (int ks = 0; ks < 4; ++ks) {
                int off = rb + fq * 16 + ks * 64;
                a3[ks] = *reinterpret_cast<const bf16x8*>(lds + 32768 + (off ^ swz));
            }
            f32x4 acc3[2];
#pragma unroll
            for (int j = 0; j < 2; ++j) acc3[j] = (f32x4){0.f, 0.f, 0.f, 0.f};
#pragma unroll
            for (int nt = 0; nt < 2; ++nt)
#pragma unroll
                for (int ks = 0; ks < 4; ++ks)
                    acc3[nt] = __builtin_amdgcn_mfma_f32_16x16x32_bf16(a3[ks], w3f[nt][ks], acc3[nt], 0, 0, 0);
#pragma unroll
            for (int i = 0; i < 4; ++i) {
                int gm = rowBase + half * 32 + tt * 16 + fq * 4 + i;
                if (gm >= M) continue;
#pragma unroll
                for (int nt = 0; nt < 2; ++nt) {
                    int c = ch * 32 + nt * 16 + fr;
                    float v = acc3[nt][i] + b3[c];
                    out[(size_t)gm * 64 + c] = v > 0.f ? v : 0.f;
                }
            }
        }
    }
}

// ---------------------------------------------------------------------------
extern "C" void kernel_launch(void* const* d_in, const int* in_sizes, int n_in,
                              void* d_out, int out_size, void* d_ws, size_t ws_size,
                              hipStream_t stream) {
    const float* x   = (const float*)d_in[0];
    const int*   ei  = (const int*)d_in[1];
    const float* W1l = (const float*)d_in[2];
    const float* b1l = (const float*)d_in[3];
    const float* W1r = (const float*)d_in[4];
    const float* W2l = (const float*)d_in[5];
    const float* b2l = (const float*)d_in[6];
    const float* W2r = (const float*)d_in[7];
    const float* W3  = (const float*)d_in[8];
    const float* b3  = (const float*)d_in[9];
    float* out = (float*)d_out;

    const int NN = N_NODES, E = N_EDGES;

    char* base = (char*)d_ws;
    // padded feature buffers: N_PAD rows x 256 B = 12,812,288 each
    unsigned short* xb    = (unsigned short*)(base + 0);
    unsigned short* h1b   = (unsigned short*)(base + 12812288);
    unsigned short* meanb = (unsigned short*)(base + 25624576);
    unsigned char*  x8    = (unsigned char*) (base + 38436864);  // 6,400,000
    unsigned char*  h18   = (unsigned char*) (base + 44836864);  // 6,400,000
    unsigned short* w1lb  = (unsigned short*)(base + 51236864);
    unsigned short* w1rb  = (unsigned short*)(base + 51269632);
    unsigned short* w2lb  = (unsigned short*)(base + 51302400);
    unsigned short* w2rb  = (unsigned short*)(base + 51335168);
    unsigned short* w3b   = (unsigned short*)(base + 51367936);  // 16,384
    int* offs             = (int*)(base + 51384320);             // 200,064
    int* bucketCount      = (int*)(base + 51584384);             // 1,600 (+pad)
    int* csr              = (int*)(base + 51586048);             // 3,200,000
    unsigned long long* pairBuf = (unsigned long long*)(base + 54786048); // 12,812,288

    zero_bc<<<1, 512, 0, stream>>>(bucketCount);

    const int PREP_BLKS = (XITEMS + WITEMS + 511) / 512;   // 3161
    prep_scatter<<<SCAT_BLKS + PREP_BLKS, 512, 0, stream>>>(
        x, xb, x8, W1l, W1r, W2l, W2r, W3, w1lb, w1rb, w2lb, w2rb, w3b,
        ei, bucketCount, pairBuf);

    csr_sort<<<NBUCK, 512, 0, stream>>>(pairBuf, bucketCount, offs, csr, NN);

    const int AGG_BLK = (NN * 16 + 255) / 256;   // 3125
    const int GB64 = (NN + 63) / 64;             // 782

    // Layer 1 (gemm writes h1b bf16 + h18 fp8 in one pass)
    aggregate_fp8<<<AGG_BLK, 256, 0, stream>>>(x8, offs, csr, meanb, NN);
    gemm_k<false><<<GB64, 256, 0, stream>>>(meanb, w1lb, xb, w1rb, b1l,
                                            nullptr, nullptr, h1b, h18, NN);

    // Layer 2 + head
    aggregate_fp8<<<AGG_BLK, 256, 0, stream>>>(h18, offs, csr, meanb, NN);
    gemm_k<true><<<GB64, 256, 0, stream>>>(meanb, w2lb, h1b, w2rb, b2l,
                                           w3b, b3, out, nullptr, NN);
}